// Round 5
// baseline (1348.734 us; speedup 1.0000x reference)
//
#include <hip/hip_runtime.h>
#include <hip/hip_bf16.h>
#include <cstddef>
#include <cstdint>

// ---------------------------------------------------------------------------
// PointNet++ encoder for MI355X. Sizes fixed per reference:
// B=8, N1=8192, S1=512 (ns=32, r=0.2), S2=128 (ns=64, r=0.4),
// C1=3->O1=128, C2=131->O2=256, C3=259->O3=512, Z=256.
// ---------------------------------------------------------------------------

typedef float v2f __attribute__((ext_vector_type(2)));

__device__ __forceinline__ void fma16(float* acc, float4 a, float4 b) {
  acc[0]  = fmaf(a.x, b.x, acc[0]);
  acc[1]  = fmaf(a.x, b.y, acc[1]);
  acc[2]  = fmaf(a.x, b.z, acc[2]);
  acc[3]  = fmaf(a.x, b.w, acc[3]);
  acc[4]  = fmaf(a.y, b.x, acc[4]);
  acc[5]  = fmaf(a.y, b.y, acc[5]);
  acc[6]  = fmaf(a.y, b.z, acc[6]);
  acc[7]  = fmaf(a.y, b.w, acc[7]);
  acc[8]  = fmaf(a.z, b.x, acc[8]);
  acc[9]  = fmaf(a.z, b.y, acc[9]);
  acc[10] = fmaf(a.z, b.z, acc[10]);
  acc[11] = fmaf(a.z, b.w, acc[11]);
  acc[12] = fmaf(a.w, b.x, acc[12]);
  acc[13] = fmaf(a.w, b.y, acc[13]);
  acc[14] = fmaf(a.w, b.z, acc[14]);
  acc[15] = fmaf(a.w, b.w, acc[15]);
}

// DPP-based max step: v = max(v, dpp_shift(v)). All reduced values are >= 0,
// so bound_ctrl zero-fill is safe. VALU-only (no LDS pipe).
#define DPP_FMAX(v, ctrl)                                                     \
  (v) = fmaxf((v), __int_as_float(__builtin_amdgcn_update_dpp(                \
                 0, __float_as_int(v), (ctrl), 0xf, 0xf, true)))

__device__ __forceinline__ float wave_max_dpp(float v) {
  DPP_FMAX(v, 0x111);  // row_shr:1
  DPP_FMAX(v, 0x112);  // row_shr:2
  DPP_FMAX(v, 0x114);  // row_shr:4
  DPP_FMAX(v, 0x118);  // row_shr:8  -> lane15 of each row = row max
  DPP_FMAX(v, 0x142);  // row_bcast:15
  DPP_FMAX(v, 0x143);  // row_bcast:31 -> lane63 = wave max
  return __int_as_float(__builtin_amdgcn_readlane(__float_as_int(v), 63));
}

__device__ __forceinline__ float readlane_f(float v, int l) {
  return __int_as_float(__builtin_amdgcn_readlane(__float_as_int(v), l));
}

// ---------------------------------------------------------------------------
// FPS, round-5: one block per batch, TPB=512 (8 waves). ONE barrier/iter.
// Pre-barrier: packed-f32 scan (v_pk_add/mul codegen; fp contract OFF so
// per-element rounding == __fmul_rn/__fadd_rn) -> DPP wave max -> ballot ->
// owner lane rescans its slots and writes (wv, x, y, z) + idx to
// parity-double-buffered LDS. Post-barrier: all lanes read the 8 candidates,
// 3-level DPP max over value, ballot -> first winning wave; coords broadcast
// via readlane from the candidate already in registers (no 2nd LDS read).
// Selection uses exact bit compares; (wave,lane,slot) lexicographic order ==
// ascending global index == jnp.argmax first-index tie-break.
// ---------------------------------------------------------------------------
template<int N, int NPOINT, int TPB>
__launch_bounds__(TPB)
__global__ void fps_kernel(const float* __restrict__ xyz,
                           int* __restrict__ out_idx,
                           float* __restrict__ out_xyz) {
  constexpr int PPT = N / TPB;
  constexpr int NW = TPB / 64;
  static_assert(NW == 8, "cross-wave DPP reduce assumes 8 waves");
  static_assert(PPT == 1 || (PPT % 2) == 0, "PPT must be 1 or even");
  constexpr int PPT2 = (PPT >= 2) ? PPT / 2 : 1;
  __shared__ float4 s_cand[2][NW];
  __shared__ int s_idx[2][NW];
  const int b = blockIdx.x;
  const int t = threadIdx.x;
  const int lane = t & 63;
  const int wid = t >> 6;
  const float* xb = xyz + (size_t)b * N * 3;

  // Point storage: packed pairs (PPT>=2) or scalars (PPT==1).
  v2f px2[PPT2], py2[PPT2], pz2[PPT2], dist2[PPT2];
  float px1, py1, pz1, dist1;
  if constexpr (PPT == 1) {
    const int n = t;
    px1 = xb[n * 3 + 0];
    py1 = xb[n * 3 + 1];
    pz1 = xb[n * 3 + 2];
    dist1 = 1e10f;
  } else {
#pragma unroll
    for (int k = 0; k < PPT2; ++k) {
      const int n = t * PPT + 2 * k;
      px2[k].x = xb[n * 3 + 0];
      py2[k].x = xb[n * 3 + 1];
      pz2[k].x = xb[n * 3 + 2];
      px2[k].y = xb[n * 3 + 3];
      py2[k].y = xb[n * 3 + 4];
      pz2[k].y = xb[n * 3 + 5];
      dist2[k].x = 1e10f;
      dist2[k].y = 1e10f;
    }
  }

  int far = 0;
  float cx = xb[0], cy = xb[1], cz = xb[2];
  for (int i = 0; i < NPOINT; ++i) {
    if (t == 0) {
      out_idx[b * NPOINT + i] = far;
      float* o = out_xyz + ((size_t)b * NPOINT + i) * 3;
      o[0] = cx; o[1] = cy; o[2] = cz;
    }
    // --- scan: update min-dist, track local max (all values >= 0) ---
    float m;
    if constexpr (PPT == 1) {
#pragma clang fp contract(off)
      const float dx = px1 - cx;
      const float dy = py1 - cy;
      const float dz = pz1 - cz;
      const float d = dx * dx + dy * dy + dz * dz;
      dist1 = fminf(dist1, d);
      m = dist1;
    } else {
      const v2f c2x = {cx, cx}, c2y = {cy, cy}, c2z = {cz, cz};
      v2f m2 = {-1.0f, -1.0f};
#pragma unroll
      for (int k = 0; k < PPT2; ++k) {
#pragma clang fp contract(off)
        const v2f dx = px2[k] - c2x;
        const v2f dy = py2[k] - c2y;
        const v2f dz = pz2[k] - c2z;
        const v2f d = dx * dx + dy * dy + dz * dz;
        v2f nd;
        nd.x = fminf(dist2[k].x, d.x);
        nd.y = fminf(dist2[k].y, d.y);
        dist2[k] = nd;
        m2.x = fmaxf(m2.x, nd.x);
        m2.y = fmaxf(m2.y, nd.y);
      }
      m = fmaxf(m2.x, m2.y);
    }
    // --- per-wave candidate (pre-barrier) ---
    const float wv = wave_max_dpp(m);
    const unsigned long long cand = __ballot(m == wv);
    const int fl = __ffsll(cand) - 1;
    const int p = i & 1;
    if (lane == fl) {
      int fj = 0;
      float fx, fy, fz;
      if constexpr (PPT == 1) {
        fx = px1; fy = py1; fz = pz1;
      } else {
        fx = px2[0].x; fy = py2[0].x; fz = pz2[0].x;
        bool found = false;
#pragma unroll
        for (int k = 0; k < PPT2; ++k) {
          const bool hx = !found && (dist2[k].x == wv);
          if (hx) { fj = 2 * k; fx = px2[k].x; fy = py2[k].x; fz = pz2[k].x; found = true; }
          const bool hy = !found && (dist2[k].y == wv);
          if (hy) { fj = 2 * k + 1; fx = px2[k].y; fy = py2[k].y; fz = pz2[k].y; found = true; }
        }
      }
      s_cand[p][wid] = make_float4(wv, fx, fy, fz);
      s_idx[p][wid] = t * PPT + fj;
    }
    __syncthreads();
    // --- cross-wave winner (post-barrier, registers only after 1 read) ---
    const float4 c4 = s_cand[p][lane & 7];
    float y = c4.x;
    DPP_FMAX(y, 0x111);
    DPP_FMAX(y, 0x112);
    DPP_FMAX(y, 0x114);
    const float winner = readlane_f(y, 7);
    const unsigned long long wmask = __ballot(c4.x == winner);
    const int wstar = __ffsll(wmask) - 1;  // lane idx 0..7 == wave id
    cx = readlane_f(c4.y, wstar);
    cy = readlane_f(c4.z, wstar);
    cz = readlane_f(c4.w, wstar);
    if (t == 0) far = s_idx[p][wstar];
  }
}

// ---------------------------------------------------------------------------
// Ball query: one wave per (b,s). Stream-compact ascending indices whose
// sqrdist (reference cancellation formula) <= r^2; fill remainder with first.
// ---------------------------------------------------------------------------
template<int N, int S, int NS>
__global__ void ballq_kernel(const float* __restrict__ xyz,
                             const float* __restrict__ new_xyz,
                             int* __restrict__ out_idx,
                             float r2) {
  const int gw = (blockIdx.x * blockDim.x + threadIdx.x) >> 6;
  const int lane = threadIdx.x & 63;
  if (gw >= 8 * S) return;
  const int b = gw / S;
  const int s = gw % S;
  const float* c = new_xyz + ((size_t)b * S + s) * 3;
  const float cx = c[0], cy = c[1], cz = c[2];
  const float sa = __fadd_rn(__fadd_rn(__fmul_rn(cx, cx), __fmul_rn(cy, cy)),
                             __fmul_rn(cz, cz));
  const float* xb = xyz + (size_t)b * N * 3;
  int* out = out_idx + ((size_t)b * S + s) * NS;
  int cnt = 0;
  int first = -1;
  for (int n0 = 0; n0 < N && cnt < NS; n0 += 64) {
    const int n = n0 + lane;
    const float x = xb[n * 3 + 0];
    const float y = xb[n * 3 + 1];
    const float z = xb[n * 3 + 2];
    const float sb = __fadd_rn(__fadd_rn(__fmul_rn(x, x), __fmul_rn(y, y)),
                               __fmul_rn(z, z));
    const float dt = __fadd_rn(__fadd_rn(__fmul_rn(x, cx), __fmul_rn(y, cy)),
                               __fmul_rn(z, cz));
    const float d = __fsub_rn(__fadd_rn(sa, sb), __fmul_rn(2.0f, dt));
    const bool in = !(d > r2);
    const unsigned long long m = __ballot(in);
    if (in) {
      const int pos = cnt + __popcll(m & ((1ull << lane) - 1ull));
      if (pos < NS) out[pos] = n;
    }
    if (first < 0 && m) first = n0 + __ffsll((unsigned long long)m) - 1;
    cnt += __popcll(m);
  }
  for (int j = cnt + lane; j < NS; j += 64) out[j] = first;
}

// ---------------------------------------------------------------------------
// Layer-1 moments: x = xyz[idx] - new_xyz  (C=3). 9 sums per block -> partials.
// ---------------------------------------------------------------------------
__global__ void mom1_kernel(const float* __restrict__ xyz,
                            const float* __restrict__ l1_xyz,
                            const int* __restrict__ idx1,
                            float* __restrict__ part) {
  const int t = threadIdx.x;
  const int r = blockIdx.x * 256 + t;   // 0..131071
  const int bs = r >> 5;
  const int b = r >> 14;
  const int idx = idx1[r];
  const float* p = xyz + ((size_t)(b << 13) + idx) * 3;
  const float* q = l1_xyz + (size_t)bs * 3;
  const float x = p[0] - q[0];
  const float y = p[1] - q[1];
  const float z = p[2] - q[2];
  float vals[9] = {x, y, z, x * x, x * y, x * z, y * y, y * z, z * z};
  __shared__ float sw[4][9];
  const int lane = t & 63, wid = t >> 6;
#pragma unroll
  for (int v = 0; v < 9; ++v) {
    float a = vals[v];
#pragma unroll
    for (int off = 32; off; off >>= 1) a += __shfl_xor(a, off);
    if (lane == 0) sw[wid][v] = a;
  }
  __syncthreads();
  if (t == 0) {
#pragma unroll
    for (int v = 0; v < 9; ++v)
      part[blockIdx.x * 12 + v] = sw[0][v] + sw[1][v] + sw[2][v] + sw[3][v];
  }
}

__global__ void stats1_kernel(const float* __restrict__ part,
                              const float* __restrict__ w1,
                              const float* __restrict__ b1,
                              const float* __restrict__ g1,
                              const float* __restrict__ be1,
                              float* __restrict__ ss1) {
  __shared__ double sm[9];
  const int t = threadIdx.x;
  if (t < 9) {
    double a = 0.0;
    for (int k = 0; k < 512; ++k) a += (double)part[k * 12 + t];
    sm[t] = a;
  }
  __syncthreads();
  const double n = 131072.0;
  const double mu0 = sm[0] / n, mu1 = sm[1] / n, mu2 = sm[2] / n;
  const double C00 = sm[3] / n - mu0 * mu0;
  const double C01 = sm[4] / n - mu0 * mu1;
  const double C02 = sm[5] / n - mu0 * mu2;
  const double C11 = sm[6] / n - mu1 * mu1;
  const double C12 = sm[7] / n - mu1 * mu2;
  const double C22 = sm[8] / n - mu2 * mu2;
  if (t < 128) {
    const double w0 = w1[t * 3], w1_ = w1[t * 3 + 1], w2 = w1[t * 3 + 2];
    const double mh = w0 * mu0 + w1_ * mu1 + w2 * mu2 + (double)b1[t];
    const double var = w0 * w0 * C00 + w1_ * w1_ * C11 + w2 * w2 * C22 +
                       2.0 * (w0 * w1_ * C01 + w0 * w2 * C02 + w1_ * w2 * C12);
    const float scale = g1[t] / sqrtf((float)var + 1e-5f);
    const float shift = be1[t] - (float)mh * scale;
    ss1[t * 2] = scale;
    ss1[t * 2 + 1] = shift;
  }
}

// ---------------------------------------------------------------------------
// Layer-1 fused conv+BN+relu+max: one block per (b,s), thread = channel o.
// ---------------------------------------------------------------------------
__global__ void conv1max_kernel(const float* __restrict__ xyz,
                                const float* __restrict__ l1_xyz,
                                const int* __restrict__ idx1,
                                const float* __restrict__ w1,
                                const float* __restrict__ b1,
                                const float* __restrict__ ss1,
                                float* __restrict__ l1_pts) {
  const int bs = blockIdx.x;
  const int b = bs >> 9;
  const int t = threadIdx.x;  // 128
  __shared__ float sx[32][3];
  if (t < 32) {
    const int idx = idx1[bs * 32 + t];
    const float* p = xyz + ((size_t)(b << 13) + idx) * 3;
    const float* q = l1_xyz + (size_t)bs * 3;
    sx[t][0] = p[0] - q[0];
    sx[t][1] = p[1] - q[1];
    sx[t][2] = p[2] - q[2];
  }
  __syncthreads();
  const float w0 = w1[t * 3], wa = w1[t * 3 + 1], wb = w1[t * 3 + 2];
  const float bo = b1[t];
  float hmax = -1e30f, hmin = 1e30f;
#pragma unroll 8
  for (int k = 0; k < 32; ++k) {
    const float h = sx[k][0] * w0 + sx[k][1] * wa + sx[k][2] * wb + bo;
    hmax = fmaxf(hmax, h);
    hmin = fminf(hmin, h);
  }
  const float scale = ss1[t * 2], shift = ss1[t * 2 + 1];
  const float hsel = (scale >= 0.f) ? hmax : hmin;
  l1_pts[(size_t)bs * 128 + t] = fmaxf(hsel * scale + shift, 0.0f);
}

// ---------------------------------------------------------------------------
// Layer-2 moments: rows (b,s,k) of x2 (C=131, padded 132). Partial sums of
// S2 = X^T X (full 132x132) and S1 per block; deterministic reduce after.
// ---------------------------------------------------------------------------
#define MOM2_BLOCKS 256
#define MOM2_S2 (132 * 132)            // 17424
#define MOM2_STRIDE (MOM2_S2 + 132)    // 17556

__global__ __launch_bounds__(256)
void mom2_kernel(const float* __restrict__ l1_xyz,
                 const float* __restrict__ l1_pts,
                 const float* __restrict__ l2_xyz,
                 const int* __restrict__ idx2,
                 float* __restrict__ part) {
  __shared__ __align__(16) float xs[64 * 132];
  const int t = threadIdx.x;
  const int blk = blockIdx.x;
  float acc[5][16];
#pragma unroll
  for (int tt = 0; tt < 5; ++tt)
#pragma unroll
    for (int j = 0; j < 16; ++j) acc[tt][j] = 0.f;
  float s1 = 0.f;
  const int rbase = blk * 256;
  for (int sb = 0; sb < 4; ++sb) {
    __syncthreads();
    for (int e = t; e < 64 * 131; e += 256) {
      const int rr = e / 131, cc = e % 131;
      const int r = rbase + sb * 64 + rr;
      const int b = r >> 13;
      const int s = (r >> 6) & 127;
      const int idx = idx2[r];
      float v;
      if (cc < 3)
        v = l1_xyz[((size_t)(b << 9) + idx) * 3 + cc] -
            l2_xyz[((size_t)(b << 7) + s) * 3 + cc];
      else
        v = l1_pts[((size_t)(b << 9) + idx) * 128 + (cc - 3)];
      xs[rr * 132 + cc] = v;
    }
    if (t < 64) xs[t * 132 + 131] = 0.f;
    __syncthreads();
#pragma unroll
    for (int tt = 0; tt < 5; ++tt) {
      const int tile = t + tt * 256;
      if (tile < 33 * 33) {
        const int i0 = (tile % 33) * 4;
        const int j0 = (tile / 33) * 4;
        for (int r = 0; r < 64; ++r) {
          const float4 a = *(const float4*)&xs[r * 132 + i0];
          const float4 bb = *(const float4*)&xs[r * 132 + j0];
          fma16(acc[tt], a, bb);
        }
      }
    }
    if (t < 132) {
      for (int r = 0; r < 64; ++r) s1 += xs[r * 132 + t];
    }
  }
  float* pb = part + (size_t)blk * MOM2_STRIDE;
#pragma unroll
  for (int tt = 0; tt < 5; ++tt) {
    const int tile = t + tt * 256;
    if (tile < 33 * 33) {
      const int i0 = (tile % 33) * 4;
      const int j0 = (tile / 33) * 4;
#pragma unroll
      for (int ii = 0; ii < 4; ++ii)
#pragma unroll
        for (int jj = 0; jj < 4; ++jj)
          pb[(i0 + ii) * 132 + (j0 + jj)] = acc[tt][ii * 4 + jj];
    }
  }
  if (t < 132) pb[MOM2_S2 + t] = s1;
}

__global__ void reduce2_kernel(const float* __restrict__ part,
                               double* __restrict__ out) {
  const int e = blockIdx.x * 256 + threadIdx.x;
  if (e >= MOM2_STRIDE) return;
  double a = 0.0;
  for (int k = 0; k < MOM2_BLOCKS; ++k)
    a += (double)part[(size_t)k * MOM2_STRIDE + e];
  out[e] = a;
}

__global__ void stats2_kernel(const double* __restrict__ mom,
                              const float* __restrict__ w2,
                              const float* __restrict__ b2,
                              const float* __restrict__ g2,
                              const float* __restrict__ be2,
                              float* __restrict__ ss2) {
  const int o = blockIdx.x;
  const int t = threadIdx.x;  // 128
  const float* w = w2 + o * 131;
  double q = 0.0, md = 0.0;
  for (int i = t; i < 131; i += 128) {
    const double wi = (double)w[i];
    double di = 0.0;
    for (int j = 0; j < 131; ++j) di += mom[i * 132 + j] * (double)w[j];
    q += wi * di;
    md += wi * mom[MOM2_S2 + i];
  }
  __shared__ double sq[128], smd[128];
  sq[t] = q;
  smd[t] = md;
  __syncthreads();
  for (int off = 64; off; off >>= 1) {
    if (t < off) { sq[t] += sq[t + off]; smd[t] += smd[t + off]; }
    __syncthreads();
  }
  if (t == 0) {
    const double n = 65536.0;
    const double mdot = smd[0] / n;
    const double var = sq[0] / n - mdot * mdot;
    const double mean = mdot + (double)b2[o];
    const float scale = g2[o] / sqrtf((float)var + 1e-5f);
    const float shift = be2[o] - (float)mean * scale;
    ss2[o * 2] = scale;
    ss2[o * 2 + 1] = shift;
  }
}

// ---------------------------------------------------------------------------
// Layer-2 fused conv+BN+relu+max: block per (b,s). 64 rows (k) x 256 o,
// K=131 via LDS tiles; o in chunks of 32. 128 threads = 16 ty x 8 tx, 4x4.
// ---------------------------------------------------------------------------
__global__ __launch_bounds__(128)
void conv2max_kernel(const float* __restrict__ l1_xyz,
                     const float* __restrict__ l1_pts,
                     const float* __restrict__ l2_xyz,
                     const int* __restrict__ idx2,
                     const float* __restrict__ w2,
                     const float* __restrict__ b2,
                     const float* __restrict__ ss2,
                     float* __restrict__ l2_pts) {
  __shared__ __align__(16) float xT[131 * 68];  // [c][k] stride 68
  __shared__ __align__(16) float wT[131 * 36];  // [c][oo] stride 36
  __shared__ float red[16 * 32];
  const int bs = blockIdx.x;  // b*128+s
  const int b = bs >> 7;
  const int t = threadIdx.x;
  for (int e = t; e < 64 * 131; e += 128) {
    const int k = e / 131, cc = e % 131;
    const int idx = idx2[bs * 64 + k];
    float v;
    if (cc < 3)
      v = l1_xyz[((size_t)(b << 9) + idx) * 3 + cc] - l2_xyz[(size_t)bs * 3 + cc];
    else
      v = l1_pts[((size_t)(b << 9) + idx) * 128 + (cc - 3)];
    xT[cc * 68 + k] = v;
  }
  const int ty = t >> 3;   // 0..15 -> k quad
  const int tx = t & 7;    // 0..7  -> o quad within 32-chunk
  for (int oc = 0; oc < 8; ++oc) {
    __syncthreads();
    for (int e = t; e < 32 * 131; e += 128) {
      const int oo = e / 131, cc = e % 131;
      wT[cc * 36 + oo] = w2[(oc * 32 + oo) * 131 + cc];
    }
    __syncthreads();
    float acc[16];
#pragma unroll
    for (int j = 0; j < 16; ++j) acc[j] = 0.f;
    for (int c = 0; c < 131; ++c) {
      const float4 a = *(const float4*)&xT[c * 68 + ty * 4];
      const float4 w4 = *(const float4*)&wT[c * 36 + tx * 4];
      fma16(acc, a, w4);
    }
#pragma unroll
    for (int oo = 0; oo < 4; ++oo) {
      const int o = oc * 32 + tx * 4 + oo;
      const float bo = b2[o];
      const float hmax = fmaxf(fmaxf(acc[0 + oo], acc[4 + oo]),
                               fmaxf(acc[8 + oo], acc[12 + oo])) + bo;
      const float hmin = fminf(fminf(acc[0 + oo], acc[4 + oo]),
                               fminf(acc[8 + oo], acc[12 + oo])) + bo;
      const float scale = ss2[o * 2], shift = ss2[o * 2 + 1];
      const float hsel = (scale >= 0.f) ? hmax : hmin;
      red[ty * 32 + tx * 4 + oo] = fmaxf(hsel * scale + shift, 0.f);
    }
    __syncthreads();
    if (t < 32) {
      float m = red[t];
#pragma unroll
      for (int w = 1; w < 16; ++w) m = fmaxf(m, red[w * 32 + t]);
      l2_pts[(size_t)bs * 256 + oc * 32 + t] = m;
    }
  }
}

// ---------------------------------------------------------------------------
// Layer-3 GEMM: h3T[o][r] = dot(x3[r], w3[o]) + b3[o]; r=b*128+k (1024),
// o (512), K=259 in chunks of 96 (zero-padded). Output transposed for stats.
// ---------------------------------------------------------------------------
__global__ __launch_bounds__(256)
void conv3_kernel(const float* __restrict__ l2_xyz,
                  const float* __restrict__ l2_pts,
                  const float* __restrict__ w3,
                  const float* __restrict__ b3,
                  float* __restrict__ h3T) {
  __shared__ __align__(16) float aT[96 * 68];  // [cc][rr] stride 68
  __shared__ __align__(16) float wT[96 * 68];  // [cc][oo] stride 68
  const int t = threadIdx.x;
  const int r0 = (blockIdx.x & 15) * 64;
  const int o0 = (blockIdx.x >> 4) * 64;
  const int ty = t >> 4, tx = t & 15;
  float acc[16];
#pragma unroll
  for (int j = 0; j < 16; ++j) acc[j] = 0.f;
  for (int c0 = 0; c0 < 259; c0 += 96) {
    __syncthreads();
    for (int e = t; e < 96 * 64; e += 256) {
      const int rr = e / 96, cc = e - rr * 96;
      const int c = c0 + cc;
      const int r = r0 + rr;
      float v = 0.f;
      if (c < 259)
        v = (c < 3) ? l2_xyz[(size_t)r * 3 + c]
                    : l2_pts[(size_t)r * 256 + (c - 3)];
      aT[cc * 68 + rr] = v;
    }
    for (int e = t; e < 96 * 64; e += 256) {
      const int oo = e / 96, cc = e - oo * 96;
      const int c = c0 + cc;
      wT[cc * 68 + oo] = (c < 259) ? w3[(size_t)(o0 + oo) * 259 + c] : 0.f;
    }
    __syncthreads();
    for (int cc = 0; cc < 96; ++cc) {
      const float4 a = *(const float4*)&aT[cc * 68 + ty * 4];
      const float4 w4 = *(const float4*)&wT[cc * 68 + tx * 4];
      fma16(acc, a, w4);
    }
  }
#pragma unroll
  for (int kk = 0; kk < 4; ++kk)
#pragma unroll
    for (int oo = 0; oo < 4; ++oo) {
      const int o = o0 + tx * 4 + oo;
      const int r = r0 + ty * 4 + kk;
      h3T[(size_t)o * 1024 + r] = acc[kk * 4 + oo] + b3[o];
    }
}

// ---------------------------------------------------------------------------
// Layer-3 BN stats + relu + per-batch max, fused. Block per channel o.
// ---------------------------------------------------------------------------
__global__ void bn3max_kernel(const float* __restrict__ h3T,
                              const float* __restrict__ g3,
                              const float* __restrict__ be3,
                              float* __restrict__ l3) {
  const int o = blockIdx.x;
  const int t = threadIdx.x;  // 256
  const float4 v = *(const float4*)&h3T[(size_t)o * 1024 + t * 4];
  double s = (double)v.x + (double)v.y + (double)v.z + (double)v.w;
  double s2 = (double)v.x * v.x + (double)v.y * v.y + (double)v.z * v.z +
              (double)v.w * v.w;
  __shared__ double sa_[256], sb_[256];
  sa_[t] = s;
  sb_[t] = s2;
  __syncthreads();
  for (int off = 128; off; off >>= 1) {
    if (t < off) { sa_[t] += sa_[t + off]; sb_[t] += sb_[t + off]; }
    __syncthreads();
  }
  const double mean = sa_[0] / 1024.0;
  const double var = sb_[0] / 1024.0 - mean * mean;
  const float scale = g3[o] / sqrtf((float)var + 1e-5f);
  const float shift = be3[o] - (float)mean * scale;
  const float hmax = fmaxf(fmaxf(v.x, v.y), fmaxf(v.z, v.w));
  const float hmin = fminf(fminf(v.x, v.y), fminf(v.z, v.w));
  const float hsel = (scale >= 0.f) ? hmax : hmin;
  __shared__ float rm[256];
  rm[t] = fmaxf(hsel * scale + shift, 0.f);
  __syncthreads();
  if (t < 8) {
    float m = rm[t * 32];
#pragma unroll
    for (int j = 1; j < 32; ++j) m = fmaxf(m, rm[t * 32 + j]);
    l3[t * 512 + o] = m;
  }
}

__global__ void final_kernel(const float* __restrict__ l3,
                             const float* __restrict__ wf,
                             const float* __restrict__ bf,
                             float* __restrict__ out) {
  const int b = blockIdx.x;
  const int t = threadIdx.x;  // 256
  __shared__ float s[512];
  s[t] = l3[b * 512 + t];
  s[t + 256] = l3[b * 512 + t + 256];
  __syncthreads();
  float acc = bf[t];
  for (int o = 0; o < 512; ++o) acc = fmaf(wf[(size_t)t * 512 + o], s[o], acc);
  out[b * 256 + t] = acc;
}

// ---------------------------------------------------------------------------
extern "C" void kernel_launch(void* const* d_in, const int* in_sizes, int n_in,
                              void* d_out, int out_size, void* d_ws, size_t ws_size,
                              hipStream_t stream) {
  (void)in_sizes; (void)n_in; (void)out_size; (void)ws_size;
  const float* xyz = (const float*)d_in[0];
  const float* w1 = (const float*)d_in[1];
  const float* b1 = (const float*)d_in[2];
  const float* g1 = (const float*)d_in[3];
  const float* be1 = (const float*)d_in[4];
  const float* w2 = (const float*)d_in[5];
  const float* b2 = (const float*)d_in[6];
  const float* g2 = (const float*)d_in[7];
  const float* be2 = (const float*)d_in[8];
  const float* w3 = (const float*)d_in[9];
  const float* b3 = (const float*)d_in[10];
  const float* g3 = (const float*)d_in[11];
  const float* be3 = (const float*)d_in[12];
  const float* wf = (const float*)d_in[13];
  const float* bf = (const float*)d_in[14];
  float* out = (float*)d_out;

  char* base = (char*)d_ws;
  size_t off = 0;
  auto alloc = [&](size_t bytes) -> char* {
    off = (off + 511) & ~(size_t)511;
    char* p = base + off;
    off += bytes;
    return p;
  };
  int* fps1_idx = (int*)alloc(8 * 512 * 4);
  float* l1_xyz = (float*)alloc(8 * 512 * 3 * 4);
  int* idx1 = (int*)alloc((size_t)8 * 512 * 32 * 4);
  float* part1 = (float*)alloc(512 * 12 * 4);
  float* ss1 = (float*)alloc(128 * 2 * 4);
  float* l1_pts = (float*)alloc((size_t)8 * 512 * 128 * 4);
  int* fps2_idx = (int*)alloc(8 * 128 * 4);
  float* l2_xyz = (float*)alloc(8 * 128 * 3 * 4);
  int* idx2 = (int*)alloc((size_t)8 * 128 * 64 * 4);
  float* part2 = (float*)alloc((size_t)MOM2_BLOCKS * MOM2_STRIDE * 4);
  double* mom2d = (double*)alloc((size_t)MOM2_STRIDE * 8);
  float* ss2 = (float*)alloc(256 * 2 * 4);
  float* l2_pts = (float*)alloc((size_t)8 * 128 * 256 * 4);
  float* h3T = (float*)alloc((size_t)512 * 1024 * 4);
  float* l3 = (float*)alloc(8 * 512 * 4);

  // Match JAX weak-type promotion: radius*radius in double, then cast to f32.
  const float r2_1 = (float)(0.2 * 0.2);
  const float r2_2 = (float)(0.4 * 0.4);

  fps_kernel<8192, 512, 512><<<8, 512, 0, stream>>>(xyz, fps1_idx, l1_xyz);
  ballq_kernel<8192, 512, 32><<<1024, 256, 0, stream>>>(xyz, l1_xyz, idx1, r2_1);
  mom1_kernel<<<512, 256, 0, stream>>>(xyz, l1_xyz, idx1, part1);
  stats1_kernel<<<1, 128, 0, stream>>>(part1, w1, b1, g1, be1, ss1);
  conv1max_kernel<<<4096, 128, 0, stream>>>(xyz, l1_xyz, idx1, w1, b1, ss1, l1_pts);
  fps_kernel<512, 128, 512><<<8, 512, 0, stream>>>(l1_xyz, fps2_idx, l2_xyz);
  ballq_kernel<512, 128, 64><<<256, 256, 0, stream>>>(l1_xyz, l2_xyz, idx2, r2_2);
  mom2_kernel<<<MOM2_BLOCKS, 256, 0, stream>>>(l1_xyz, l1_pts, l2_xyz, idx2, part2);
  reduce2_kernel<<<(MOM2_STRIDE + 255) / 256, 256, 0, stream>>>(part2, mom2d);
  stats2_kernel<<<256, 128, 0, stream>>>(mom2d, w2, b2, g2, be2, ss2);
  conv2max_kernel<<<1024, 128, 0, stream>>>(l1_xyz, l1_pts, l2_xyz, idx2, w2, b2,
                                            ss2, l2_pts);
  conv3_kernel<<<128, 256, 0, stream>>>(l2_xyz, l2_pts, w3, b3, h3T);
  bn3max_kernel<<<512, 256, 0, stream>>>(h3T, g3, be3, l3);
  final_kernel<<<8, 256, 0, stream>>>(l3, wf, bf, out);
}

// Round 6
// 1234.776 us; speedup vs baseline: 1.0923x; 1.0923x over previous
//
#include <hip/hip_runtime.h>
#include <hip/hip_bf16.h>
#include <cstddef>
#include <cstdint>

// ---------------------------------------------------------------------------
// PointNet++ encoder for MI355X. Sizes fixed per reference:
// B=8, N1=8192, S1=512 (ns=32, r=0.2), S2=128 (ns=64, r=0.4),
// C1=3->O1=128, C2=131->O2=256, C3=259->O3=512, Z=256.
// ---------------------------------------------------------------------------

__device__ __forceinline__ void fma16(float* acc, float4 a, float4 b) {
  acc[0]  = fmaf(a.x, b.x, acc[0]);
  acc[1]  = fmaf(a.x, b.y, acc[1]);
  acc[2]  = fmaf(a.x, b.z, acc[2]);
  acc[3]  = fmaf(a.x, b.w, acc[3]);
  acc[4]  = fmaf(a.y, b.x, acc[4]);
  acc[5]  = fmaf(a.y, b.y, acc[5]);
  acc[6]  = fmaf(a.y, b.z, acc[6]);
  acc[7]  = fmaf(a.y, b.w, acc[7]);
  acc[8]  = fmaf(a.z, b.x, acc[8]);
  acc[9]  = fmaf(a.z, b.y, acc[9]);
  acc[10] = fmaf(a.z, b.z, acc[10]);
  acc[11] = fmaf(a.z, b.w, acc[11]);
  acc[12] = fmaf(a.w, b.x, acc[12]);
  acc[13] = fmaf(a.w, b.y, acc[13]);
  acc[14] = fmaf(a.w, b.z, acc[14]);
  acc[15] = fmaf(a.w, b.w, acc[15]);
}

// DPP-based max step: v = max(v, dpp_shift(v)). All reduced values are >= 0,
// so bound_ctrl zero-fill is safe. VALU-only (no LDS pipe).
#define DPP_FMAX(v, ctrl)                                                     \
  (v) = fmaxf((v), __int_as_float(__builtin_amdgcn_update_dpp(                \
                 0, __float_as_int(v), (ctrl), 0xf, 0xf, true)))

__device__ __forceinline__ float wave_max_dpp(float v) {
  DPP_FMAX(v, 0x111);  // row_shr:1
  DPP_FMAX(v, 0x112);  // row_shr:2
  DPP_FMAX(v, 0x114);  // row_shr:4
  DPP_FMAX(v, 0x118);  // row_shr:8  -> lane15 of each row = row max
  DPP_FMAX(v, 0x142);  // row_bcast:15
  DPP_FMAX(v, 0x143);  // row_bcast:31 -> lane63 = wave max
  return __int_as_float(__builtin_amdgcn_readlane(__float_as_int(v), 63));
}

__device__ __forceinline__ float readlane_f(float v, int l) {
  return __int_as_float(__builtin_amdgcn_readlane(__float_as_int(v), l));
}

// ---------------------------------------------------------------------------
// FPS (multi-wave, round-4 verified best): one block per batch, TPB=512
// (8 waves). Per iteration: scalar scan -> DPP wave max -> s_wval write ->
// barrier A -> ds_read s_wval[lane&7] -> 3-level DPP row max -> readlane
// winner -> ballot -> first wave -> owner lane rescans slots, writes float4
// pick -> barrier B -> broadcast b128 read of pick.
// Selection uses exact bit compares; (wave,lane,slot) lexicographic order ==
// ascending global index == jnp.argmax first-index tie-break. Distance math
// bit-identical to reference (plain f32 ops, same association).
// NOTE (R5 post-mortem): v2f packed scan + single-barrier variant REGRESSED
// 641->746 us (bad pk codegen; dependent DPP/readlane chain no cheaper than
// a barrier). Do not re-introduce without disasm evidence.
// ---------------------------------------------------------------------------
template<int N, int NPOINT, int TPB>
__launch_bounds__(TPB)
__global__ void fps_kernel(const float* __restrict__ xyz,
                           int* __restrict__ out_idx,
                           float* __restrict__ out_xyz) {
  constexpr int PPT = N / TPB;
  constexpr int NW = TPB / 64;
  static_assert(NW == 8, "cross-wave DPP reduce assumes 8 waves");
  __shared__ float s_wval[NW];
  __shared__ float4 s_pick;
  const int b = blockIdx.x;
  const int t = threadIdx.x;
  const int lane = t & 63;
  const int wid = t >> 6;
  const float* xb = xyz + (size_t)b * N * 3;
  float px[PPT], py[PPT], pz[PPT], dist[PPT];
#pragma unroll
  for (int j = 0; j < PPT; ++j) {
    const int n = t * PPT + j;
    px[j] = xb[n * 3 + 0];
    py[j] = xb[n * 3 + 1];
    pz[j] = xb[n * 3 + 2];
    dist[j] = 1e10f;
  }
  int far = 0;
  float cx = xb[0], cy = xb[1], cz = xb[2];
  for (int i = 0; i < NPOINT; ++i) {
    if (t == 0) {
      out_idx[b * NPOINT + i] = far;
      float* o = out_xyz + ((size_t)b * NPOINT + i) * 3;
      o[0] = cx; o[1] = cy; o[2] = cz;
    }
    // Value-only scan: update min-dist, track local max (all values >= 0).
    float m = -1.0f;
#pragma unroll
    for (int j = 0; j < PPT; ++j) {
      const float dx = __fsub_rn(px[j], cx);
      const float dy = __fsub_rn(py[j], cy);
      const float dz = __fsub_rn(pz[j], cz);
      const float d = __fadd_rn(__fadd_rn(__fmul_rn(dx, dx), __fmul_rn(dy, dy)),
                                __fmul_rn(dz, dz));
      const float nd = fminf(dist[j], d);
      dist[j] = nd;
      m = fmaxf(m, nd);
    }
    const float wv = wave_max_dpp(m);
    if (lane == 0) s_wval[wid] = wv;
    __syncthreads();
    // Winner value: each lane reads one wave max (pattern repeats per 8
    // lanes), 3-level DPP row reduce; lane7 of row0 = global winner.
    float x = s_wval[lane & 7];
    float y = x;
    DPP_FMAX(y, 0x111);
    DPP_FMAX(y, 0x112);
    DPP_FMAX(y, 0x114);
    const float winner =
        __int_as_float(__builtin_amdgcn_readlane(__float_as_int(y), 7));
    // First wave achieving the winner: ffs over the repeating pattern gives
    // a lane index in 0..7 == wave id.
    const unsigned long long wmask = __ballot(x == winner);
    const int first_w = __ffsll(wmask) - 1;
    if (wid == first_w) {
      const unsigned long long cand = __ballot(m == winner);
      const int fl = __ffsll(cand) - 1;
      if (lane == fl) {
        int fj = 0;
        float fx = px[0], fy = py[0], fz = pz[0];
        bool found = (dist[0] == winner);
#pragma unroll
        for (int j = 1; j < PPT; ++j) {
          const bool hit = !found && (dist[j] == winner);
          if (hit) { fj = j; fx = px[j]; fy = py[j]; fz = pz[j]; found = true; }
        }
        s_pick = make_float4(__int_as_float(t * PPT + fj), fx, fy, fz);
      }
    }
    __syncthreads();
    const float4 pk = s_pick;
    far = __float_as_int(pk.x);
    cx = pk.y; cy = pk.z; cz = pk.w;
  }
}

// ---------------------------------------------------------------------------
// FPS (single-wave): N small enough for one wave (PPT = N/64 slots/lane).
// No LDS, no barriers: inline compare-select scan tracks (max, idx, coords);
// DPP value-max + ballot picks first lane; coords broadcast via readlane.
// Lane-major slot layout is ascending-global, strict > keeps first slot,
// ffs keeps first lane -> exact jnp.argmax tie-break. Distance math
// bit-identical to the multi-wave version.
// ---------------------------------------------------------------------------
template<int N, int NPOINT>
__launch_bounds__(64)
__global__ void wave_fps_kernel(const float* __restrict__ xyz,
                                int* __restrict__ out_idx,
                                float* __restrict__ out_xyz) {
  constexpr int PPT = N / 64;
  const int b = blockIdx.x;
  const int lane = threadIdx.x;
  const float* xb = xyz + (size_t)b * N * 3;
  float px[PPT], py[PPT], pz[PPT], dist[PPT];
#pragma unroll
  for (int j = 0; j < PPT; ++j) {
    const int n = lane * PPT + j;
    px[j] = xb[n * 3 + 0];
    py[j] = xb[n * 3 + 1];
    pz[j] = xb[n * 3 + 2];
    dist[j] = 1e10f;
  }
  int far = 0;
  float cx = xb[0], cy = xb[1], cz = xb[2];
  for (int i = 0; i < NPOINT; ++i) {
    if (lane == 0) {
      out_idx[b * NPOINT + i] = far;
      float* o = out_xyz + ((size_t)b * NPOINT + i) * 3;
      o[0] = cx; o[1] = cy; o[2] = cz;
    }
    float m = -1.0f;
    int mj = 0;
    float mx = px[0], my = py[0], mz = pz[0];
#pragma unroll
    for (int j = 0; j < PPT; ++j) {
      const float dx = __fsub_rn(px[j], cx);
      const float dy = __fsub_rn(py[j], cy);
      const float dz = __fsub_rn(pz[j], cz);
      const float d = __fadd_rn(__fadd_rn(__fmul_rn(dx, dx), __fmul_rn(dy, dy)),
                                __fmul_rn(dz, dz));
      const float nd = fminf(dist[j], d);
      dist[j] = nd;
      const bool better = nd > m;  // strict: first slot wins ties
      m = better ? nd : m;
      mj = better ? j : mj;
      mx = better ? px[j] : mx;
      my = better ? py[j] : my;
      mz = better ? pz[j] : mz;
    }
    const float wv = wave_max_dpp(m);
    const unsigned long long cand = __ballot(m == wv);
    const int fl = __ffsll(cand) - 1;  // first lane == smallest global index
    far = __builtin_amdgcn_readlane(lane * PPT + mj, fl);
    cx = readlane_f(mx, fl);
    cy = readlane_f(my, fl);
    cz = readlane_f(mz, fl);
  }
}

// ---------------------------------------------------------------------------
// Ball query: one wave per (b,s). Stream-compact ascending indices whose
// sqrdist (reference cancellation formula) <= r^2; fill remainder with first.
// ---------------------------------------------------------------------------
template<int N, int S, int NS>
__global__ void ballq_kernel(const float* __restrict__ xyz,
                             const float* __restrict__ new_xyz,
                             int* __restrict__ out_idx,
                             float r2) {
  const int gw = (blockIdx.x * blockDim.x + threadIdx.x) >> 6;
  const int lane = threadIdx.x & 63;
  if (gw >= 8 * S) return;
  const int b = gw / S;
  const int s = gw % S;
  const float* c = new_xyz + ((size_t)b * S + s) * 3;
  const float cx = c[0], cy = c[1], cz = c[2];
  const float sa = __fadd_rn(__fadd_rn(__fmul_rn(cx, cx), __fmul_rn(cy, cy)),
                             __fmul_rn(cz, cz));
  const float* xb = xyz + (size_t)b * N * 3;
  int* out = out_idx + ((size_t)b * S + s) * NS;
  int cnt = 0;
  int first = -1;
  for (int n0 = 0; n0 < N && cnt < NS; n0 += 64) {
    const int n = n0 + lane;
    const float x = xb[n * 3 + 0];
    const float y = xb[n * 3 + 1];
    const float z = xb[n * 3 + 2];
    const float sb = __fadd_rn(__fadd_rn(__fmul_rn(x, x), __fmul_rn(y, y)),
                               __fmul_rn(z, z));
    const float dt = __fadd_rn(__fadd_rn(__fmul_rn(x, cx), __fmul_rn(y, cy)),
                               __fmul_rn(z, cz));
    const float d = __fsub_rn(__fadd_rn(sa, sb), __fmul_rn(2.0f, dt));
    const bool in = !(d > r2);
    const unsigned long long m = __ballot(in);
    if (in) {
      const int pos = cnt + __popcll(m & ((1ull << lane) - 1ull));
      if (pos < NS) out[pos] = n;
    }
    if (first < 0 && m) first = n0 + __ffsll((unsigned long long)m) - 1;
    cnt += __popcll(m);
  }
  for (int j = cnt + lane; j < NS; j += 64) out[j] = first;
}

// ---------------------------------------------------------------------------
// Layer-1 moments: x = xyz[idx] - new_xyz  (C=3). 9 sums per block -> partials.
// ---------------------------------------------------------------------------
__global__ void mom1_kernel(const float* __restrict__ xyz,
                            const float* __restrict__ l1_xyz,
                            const int* __restrict__ idx1,
                            float* __restrict__ part) {
  const int t = threadIdx.x;
  const int r = blockIdx.x * 256 + t;   // 0..131071
  const int bs = r >> 5;
  const int b = r >> 14;
  const int idx = idx1[r];
  const float* p = xyz + ((size_t)(b << 13) + idx) * 3;
  const float* q = l1_xyz + (size_t)bs * 3;
  const float x = p[0] - q[0];
  const float y = p[1] - q[1];
  const float z = p[2] - q[2];
  float vals[9] = {x, y, z, x * x, x * y, x * z, y * y, y * z, z * z};
  __shared__ float sw[4][9];
  const int lane = t & 63, wid = t >> 6;
#pragma unroll
  for (int v = 0; v < 9; ++v) {
    float a = vals[v];
#pragma unroll
    for (int off = 32; off; off >>= 1) a += __shfl_xor(a, off);
    if (lane == 0) sw[wid][v] = a;
  }
  __syncthreads();
  if (t == 0) {
#pragma unroll
    for (int v = 0; v < 9; ++v)
      part[blockIdx.x * 12 + v] = sw[0][v] + sw[1][v] + sw[2][v] + sw[3][v];
  }
}

__global__ void stats1_kernel(const float* __restrict__ part,
                              const float* __restrict__ w1,
                              const float* __restrict__ b1,
                              const float* __restrict__ g1,
                              const float* __restrict__ be1,
                              float* __restrict__ ss1) {
  __shared__ double sm[9];
  const int t = threadIdx.x;
  if (t < 9) {
    double a = 0.0;
    for (int k = 0; k < 512; ++k) a += (double)part[k * 12 + t];
    sm[t] = a;
  }
  __syncthreads();
  const double n = 131072.0;
  const double mu0 = sm[0] / n, mu1 = sm[1] / n, mu2 = sm[2] / n;
  const double C00 = sm[3] / n - mu0 * mu0;
  const double C01 = sm[4] / n - mu0 * mu1;
  const double C02 = sm[5] / n - mu0 * mu2;
  const double C11 = sm[6] / n - mu1 * mu1;
  const double C12 = sm[7] / n - mu1 * mu2;
  const double C22 = sm[8] / n - mu2 * mu2;
  if (t < 128) {
    const double w0 = w1[t * 3], w1_ = w1[t * 3 + 1], w2 = w1[t * 3 + 2];
    const double mh = w0 * mu0 + w1_ * mu1 + w2 * mu2 + (double)b1[t];
    const double var = w0 * w0 * C00 + w1_ * w1_ * C11 + w2 * w2 * C22 +
                       2.0 * (w0 * w1_ * C01 + w0 * w2 * C02 + w1_ * w2 * C12);
    const float scale = g1[t] / sqrtf((float)var + 1e-5f);
    const float shift = be1[t] - (float)mh * scale;
    ss1[t * 2] = scale;
    ss1[t * 2 + 1] = shift;
  }
}

// ---------------------------------------------------------------------------
// Layer-1 fused conv+BN+relu+max: one block per (b,s), thread = channel o.
// ---------------------------------------------------------------------------
__global__ void conv1max_kernel(const float* __restrict__ xyz,
                                const float* __restrict__ l1_xyz,
                                const int* __restrict__ idx1,
                                const float* __restrict__ w1,
                                const float* __restrict__ b1,
                                const float* __restrict__ ss1,
                                float* __restrict__ l1_pts) {
  const int bs = blockIdx.x;
  const int b = bs >> 9;
  const int t = threadIdx.x;  // 128
  __shared__ float sx[32][3];
  if (t < 32) {
    const int idx = idx1[bs * 32 + t];
    const float* p = xyz + ((size_t)(b << 13) + idx) * 3;
    const float* q = l1_xyz + (size_t)bs * 3;
    sx[t][0] = p[0] - q[0];
    sx[t][1] = p[1] - q[1];
    sx[t][2] = p[2] - q[2];
  }
  __syncthreads();
  const float w0 = w1[t * 3], wa = w1[t * 3 + 1], wb = w1[t * 3 + 2];
  const float bo = b1[t];
  float hmax = -1e30f, hmin = 1e30f;
#pragma unroll 8
  for (int k = 0; k < 32; ++k) {
    const float h = sx[k][0] * w0 + sx[k][1] * wa + sx[k][2] * wb + bo;
    hmax = fmaxf(hmax, h);
    hmin = fminf(hmin, h);
  }
  const float scale = ss1[t * 2], shift = ss1[t * 2 + 1];
  const float hsel = (scale >= 0.f) ? hmax : hmin;
  l1_pts[(size_t)bs * 128 + t] = fmaxf(hsel * scale + shift, 0.0f);
}

// ---------------------------------------------------------------------------
// Layer-2 moments: rows (b,s,k) of x2 (C=131, padded 132). Partial sums of
// S2 = X^T X (full 132x132) and S1 per block; deterministic reduce after.
// ---------------------------------------------------------------------------
#define MOM2_BLOCKS 256
#define MOM2_S2 (132 * 132)            // 17424
#define MOM2_STRIDE (MOM2_S2 + 132)    // 17556

__global__ __launch_bounds__(256)
void mom2_kernel(const float* __restrict__ l1_xyz,
                 const float* __restrict__ l1_pts,
                 const float* __restrict__ l2_xyz,
                 const int* __restrict__ idx2,
                 float* __restrict__ part) {
  __shared__ __align__(16) float xs[64 * 132];
  const int t = threadIdx.x;
  const int blk = blockIdx.x;
  float acc[5][16];
#pragma unroll
  for (int tt = 0; tt < 5; ++tt)
#pragma unroll
    for (int j = 0; j < 16; ++j) acc[tt][j] = 0.f;
  float s1 = 0.f;
  const int rbase = blk * 256;
  for (int sb = 0; sb < 4; ++sb) {
    __syncthreads();
    for (int e = t; e < 64 * 131; e += 256) {
      const int rr = e / 131, cc = e % 131;
      const int r = rbase + sb * 64 + rr;
      const int b = r >> 13;
      const int s = (r >> 6) & 127;
      const int idx = idx2[r];
      float v;
      if (cc < 3)
        v = l1_xyz[((size_t)(b << 9) + idx) * 3 + cc] -
            l2_xyz[((size_t)(b << 7) + s) * 3 + cc];
      else
        v = l1_pts[((size_t)(b << 9) + idx) * 128 + (cc - 3)];
      xs[rr * 132 + cc] = v;
    }
    if (t < 64) xs[t * 132 + 131] = 0.f;
    __syncthreads();
#pragma unroll
    for (int tt = 0; tt < 5; ++tt) {
      const int tile = t + tt * 256;
      if (tile < 33 * 33) {
        const int i0 = (tile % 33) * 4;
        const int j0 = (tile / 33) * 4;
        for (int r = 0; r < 64; ++r) {
          const float4 a = *(const float4*)&xs[r * 132 + i0];
          const float4 bb = *(const float4*)&xs[r * 132 + j0];
          fma16(acc[tt], a, bb);
        }
      }
    }
    if (t < 132) {
      for (int r = 0; r < 64; ++r) s1 += xs[r * 132 + t];
    }
  }
  float* pb = part + (size_t)blk * MOM2_STRIDE;
#pragma unroll
  for (int tt = 0; tt < 5; ++tt) {
    const int tile = t + tt * 256;
    if (tile < 33 * 33) {
      const int i0 = (tile % 33) * 4;
      const int j0 = (tile / 33) * 4;
#pragma unroll
      for (int ii = 0; ii < 4; ++ii)
#pragma unroll
        for (int jj = 0; jj < 4; ++jj)
          pb[(i0 + ii) * 132 + (j0 + jj)] = acc[tt][ii * 4 + jj];
    }
  }
  if (t < 132) pb[MOM2_S2 + t] = s1;
}

__global__ void reduce2_kernel(const float* __restrict__ part,
                               double* __restrict__ out) {
  const int e = blockIdx.x * 256 + threadIdx.x;
  if (e >= MOM2_STRIDE) return;
  double a = 0.0;
  for (int k = 0; k < MOM2_BLOCKS; ++k)
    a += (double)part[(size_t)k * MOM2_STRIDE + e];
  out[e] = a;
}

__global__ void stats2_kernel(const double* __restrict__ mom,
                              const float* __restrict__ w2,
                              const float* __restrict__ b2,
                              const float* __restrict__ g2,
                              const float* __restrict__ be2,
                              float* __restrict__ ss2) {
  const int o = blockIdx.x;
  const int t = threadIdx.x;  // 128
  const float* w = w2 + o * 131;
  double q = 0.0, md = 0.0;
  for (int i = t; i < 131; i += 128) {
    const double wi = (double)w[i];
    double di = 0.0;
    for (int j = 0; j < 131; ++j) di += mom[i * 132 + j] * (double)w[j];
    q += wi * di;
    md += wi * mom[MOM2_S2 + i];
  }
  __shared__ double sq[128], smd[128];
  sq[t] = q;
  smd[t] = md;
  __syncthreads();
  for (int off = 64; off; off >>= 1) {
    if (t < off) { sq[t] += sq[t + off]; smd[t] += smd[t + off]; }
    __syncthreads();
  }
  if (t == 0) {
    const double n = 65536.0;
    const double mdot = smd[0] / n;
    const double var = sq[0] / n - mdot * mdot;
    const double mean = mdot + (double)b2[o];
    const float scale = g2[o] / sqrtf((float)var + 1e-5f);
    const float shift = be2[o] - (float)mean * scale;
    ss2[o * 2] = scale;
    ss2[o * 2 + 1] = shift;
  }
}

// ---------------------------------------------------------------------------
// Layer-2 fused conv+BN+relu+max: block per (b,s). 64 rows (k) x 256 o,
// K=131 via LDS tiles; o in chunks of 32. 128 threads = 16 ty x 8 tx, 4x4.
// ---------------------------------------------------------------------------
__global__ __launch_bounds__(128)
void conv2max_kernel(const float* __restrict__ l1_xyz,
                     const float* __restrict__ l1_pts,
                     const float* __restrict__ l2_xyz,
                     const int* __restrict__ idx2,
                     const float* __restrict__ w2,
                     const float* __restrict__ b2,
                     const float* __restrict__ ss2,
                     float* __restrict__ l2_pts) {
  __shared__ __align__(16) float xT[131 * 68];  // [c][k] stride 68
  __shared__ __align__(16) float wT[131 * 36];  // [c][oo] stride 36
  __shared__ float red[16 * 32];
  const int bs = blockIdx.x;  // b*128+s
  const int b = bs >> 7;
  const int t = threadIdx.x;
  for (int e = t; e < 64 * 131; e += 128) {
    const int k = e / 131, cc = e % 131;
    const int idx = idx2[bs * 64 + k];
    float v;
    if (cc < 3)
      v = l1_xyz[((size_t)(b << 9) + idx) * 3 + cc] - l2_xyz[(size_t)bs * 3 + cc];
    else
      v = l1_pts[((size_t)(b << 9) + idx) * 128 + (cc - 3)];
    xT[cc * 68 + k] = v;
  }
  const int ty = t >> 3;   // 0..15 -> k quad
  const int tx = t & 7;    // 0..7  -> o quad within 32-chunk
  for (int oc = 0; oc < 8; ++oc) {
    __syncthreads();
    for (int e = t; e < 32 * 131; e += 128) {
      const int oo = e / 131, cc = e % 131;
      wT[cc * 36 + oo] = w2[(oc * 32 + oo) * 131 + cc];
    }
    __syncthreads();
    float acc[16];
#pragma unroll
    for (int j = 0; j < 16; ++j) acc[j] = 0.f;
    for (int c = 0; c < 131; ++c) {
      const float4 a = *(const float4*)&xT[c * 68 + ty * 4];
      const float4 w4 = *(const float4*)&wT[c * 36 + tx * 4];
      fma16(acc, a, w4);
    }
#pragma unroll
    for (int oo = 0; oo < 4; ++oo) {
      const int o = oc * 32 + tx * 4 + oo;
      const float bo = b2[o];
      const float hmax = fmaxf(fmaxf(acc[0 + oo], acc[4 + oo]),
                               fmaxf(acc[8 + oo], acc[12 + oo])) + bo;
      const float hmin = fminf(fminf(acc[0 + oo], acc[4 + oo]),
                               fminf(acc[8 + oo], acc[12 + oo])) + bo;
      const float scale = ss2[o * 2], shift = ss2[o * 2 + 1];
      const float hsel = (scale >= 0.f) ? hmax : hmin;
      red[ty * 32 + tx * 4 + oo] = fmaxf(hsel * scale + shift, 0.f);
    }
    __syncthreads();
    if (t < 32) {
      float m = red[t];
#pragma unroll
      for (int w = 1; w < 16; ++w) m = fmaxf(m, red[w * 32 + t]);
      l2_pts[(size_t)bs * 256 + oc * 32 + t] = m;
    }
  }
}

// ---------------------------------------------------------------------------
// Layer-3 GEMM: h3T[o][r] = dot(x3[r], w3[o]) + b3[o]; r=b*128+k (1024),
// o (512), K=259 in chunks of 96 (zero-padded). Output transposed for stats.
// ---------------------------------------------------------------------------
__global__ __launch_bounds__(256)
void conv3_kernel(const float* __restrict__ l2_xyz,
                  const float* __restrict__ l2_pts,
                  const float* __restrict__ w3,
                  const float* __restrict__ b3,
                  float* __restrict__ h3T) {
  __shared__ __align__(16) float aT[96 * 68];  // [cc][rr] stride 68
  __shared__ __align__(16) float wT[96 * 68];  // [cc][oo] stride 68
  const int t = threadIdx.x;
  const int r0 = (blockIdx.x & 15) * 64;
  const int o0 = (blockIdx.x >> 4) * 64;
  const int ty = t >> 4, tx = t & 15;
  float acc[16];
#pragma unroll
  for (int j = 0; j < 16; ++j) acc[j] = 0.f;
  for (int c0 = 0; c0 < 259; c0 += 96) {
    __syncthreads();
    for (int e = t; e < 96 * 64; e += 256) {
      const int rr = e / 96, cc = e - rr * 96;
      const int c = c0 + cc;
      const int r = r0 + rr;
      float v = 0.f;
      if (c < 259)
        v = (c < 3) ? l2_xyz[(size_t)r * 3 + c]
                    : l2_pts[(size_t)r * 256 + (c - 3)];
      aT[cc * 68 + rr] = v;
    }
    for (int e = t; e < 96 * 64; e += 256) {
      const int oo = e / 96, cc = e - oo * 96;
      const int c = c0 + cc;
      wT[cc * 68 + oo] = (c < 259) ? w3[(size_t)(o0 + oo) * 259 + c] : 0.f;
    }
    __syncthreads();
    for (int cc = 0; cc < 96; ++cc) {
      const float4 a = *(const float4*)&aT[cc * 68 + ty * 4];
      const float4 w4 = *(const float4*)&wT[cc * 68 + tx * 4];
      fma16(acc, a, w4);
    }
  }
#pragma unroll
  for (int kk = 0; kk < 4; ++kk)
#pragma unroll
    for (int oo = 0; oo < 4; ++oo) {
      const int o = o0 + tx * 4 + oo;
      const int r = r0 + ty * 4 + kk;
      h3T[(size_t)o * 1024 + r] = acc[kk * 4 + oo] + b3[o];
    }
}

// ---------------------------------------------------------------------------
// Layer-3 BN stats + relu + per-batch max, fused. Block per channel o.
// ---------------------------------------------------------------------------
__global__ void bn3max_kernel(const float* __restrict__ h3T,
                              const float* __restrict__ g3,
                              const float* __restrict__ be3,
                              float* __restrict__ l3) {
  const int o = blockIdx.x;
  const int t = threadIdx.x;  // 256
  const float4 v = *(const float4*)&h3T[(size_t)o * 1024 + t * 4];
  double s = (double)v.x + (double)v.y + (double)v.z + (double)v.w;
  double s2 = (double)v.x * v.x + (double)v.y * v.y + (double)v.z * v.z +
              (double)v.w * v.w;
  __shared__ double sa_[256], sb_[256];
  sa_[t] = s;
  sb_[t] = s2;
  __syncthreads();
  for (int off = 128; off; off >>= 1) {
    if (t < off) { sa_[t] += sa_[t + off]; sb_[t] += sb_[t + off]; }
    __syncthreads();
  }
  const double mean = sa_[0] / 1024.0;
  const double var = sb_[0] / 1024.0 - mean * mean;
  const float scale = g3[o] / sqrtf((float)var + 1e-5f);
  const float shift = be3[o] - (float)mean * scale;
  const float hmax = fmaxf(fmaxf(v.x, v.y), fmaxf(v.z, v.w));
  const float hmin = fminf(fminf(v.x, v.y), fminf(v.z, v.w));
  const float hsel = (scale >= 0.f) ? hmax : hmin;
  __shared__ float rm[256];
  rm[t] = fmaxf(hsel * scale + shift, 0.f);
  __syncthreads();
  if (t < 8) {
    float m = rm[t * 32];
#pragma unroll
    for (int j = 1; j < 32; ++j) m = fmaxf(m, rm[t * 32 + j]);
    l3[t * 512 + o] = m;
  }
}

__global__ void final_kernel(const float* __restrict__ l3,
                             const float* __restrict__ wf,
                             const float* __restrict__ bf,
                             float* __restrict__ out) {
  const int b = blockIdx.x;
  const int t = threadIdx.x;  // 256
  __shared__ float s[512];
  s[t] = l3[b * 512 + t];
  s[t + 256] = l3[b * 512 + t + 256];
  __syncthreads();
  float acc = bf[t];
  for (int o = 0; o < 512; ++o) acc = fmaf(wf[(size_t)t * 512 + o], s[o], acc);
  out[b * 256 + t] = acc;
}

// ---------------------------------------------------------------------------
extern "C" void kernel_launch(void* const* d_in, const int* in_sizes, int n_in,
                              void* d_out, int out_size, void* d_ws, size_t ws_size,
                              hipStream_t stream) {
  (void)in_sizes; (void)n_in; (void)out_size; (void)ws_size;
  const float* xyz = (const float*)d_in[0];
  const float* w1 = (const float*)d_in[1];
  const float* b1 = (const float*)d_in[2];
  const float* g1 = (const float*)d_in[3];
  const float* be1 = (const float*)d_in[4];
  const float* w2 = (const float*)d_in[5];
  const float* b2 = (const float*)d_in[6];
  const float* g2 = (const float*)d_in[7];
  const float* be2 = (const float*)d_in[8];
  const float* w3 = (const float*)d_in[9];
  const float* b3 = (const float*)d_in[10];
  const float* g3 = (const float*)d_in[11];
  const float* be3 = (const float*)d_in[12];
  const float* wf = (const float*)d_in[13];
  const float* bf = (const float*)d_in[14];
  float* out = (float*)d_out;

  char* base = (char*)d_ws;
  size_t off = 0;
  auto alloc = [&](size_t bytes) -> char* {
    off = (off + 511) & ~(size_t)511;
    char* p = base + off;
    off += bytes;
    return p;
  };
  int* fps1_idx = (int*)alloc(8 * 512 * 4);
  float* l1_xyz = (float*)alloc(8 * 512 * 3 * 4);
  int* idx1 = (int*)alloc((size_t)8 * 512 * 32 * 4);
  float* part1 = (float*)alloc(512 * 12 * 4);
  float* ss1 = (float*)alloc(128 * 2 * 4);
  float* l1_pts = (float*)alloc((size_t)8 * 512 * 128 * 4);
  int* fps2_idx = (int*)alloc(8 * 128 * 4);
  float* l2_xyz = (float*)alloc(8 * 128 * 3 * 4);
  int* idx2 = (int*)alloc((size_t)8 * 128 * 64 * 4);
  float* part2 = (float*)alloc((size_t)MOM2_BLOCKS * MOM2_STRIDE * 4);
  double* mom2d = (double*)alloc((size_t)MOM2_STRIDE * 8);
  float* ss2 = (float*)alloc(256 * 2 * 4);
  float* l2_pts = (float*)alloc((size_t)8 * 128 * 256 * 4);
  float* h3T = (float*)alloc((size_t)512 * 1024 * 4);
  float* l3 = (float*)alloc(8 * 512 * 4);

  // Match JAX weak-type promotion: radius*radius in double, then cast to f32.
  const float r2_1 = (float)(0.2 * 0.2);
  const float r2_2 = (float)(0.4 * 0.4);

  fps_kernel<8192, 512, 512><<<8, 512, 0, stream>>>(xyz, fps1_idx, l1_xyz);
  ballq_kernel<8192, 512, 32><<<1024, 256, 0, stream>>>(xyz, l1_xyz, idx1, r2_1);
  mom1_kernel<<<512, 256, 0, stream>>>(xyz, l1_xyz, idx1, part1);
  stats1_kernel<<<1, 128, 0, stream>>>(part1, w1, b1, g1, be1, ss1);
  conv1max_kernel<<<4096, 128, 0, stream>>>(xyz, l1_xyz, idx1, w1, b1, ss1, l1_pts);
  wave_fps_kernel<512, 128><<<8, 64, 0, stream>>>(l1_xyz, fps2_idx, l2_xyz);
  ballq_kernel<512, 128, 64><<<256, 256, 0, stream>>>(l1_xyz, l2_xyz, idx2, r2_2);
  mom2_kernel<<<MOM2_BLOCKS, 256, 0, stream>>>(l1_xyz, l1_pts, l2_xyz, idx2, part2);
  reduce2_kernel<<<(MOM2_STRIDE + 255) / 256, 256, 0, stream>>>(part2, mom2d);
  stats2_kernel<<<256, 128, 0, stream>>>(mom2d, w2, b2, g2, be2, ss2);
  conv2max_kernel<<<1024, 128, 0, stream>>>(l1_xyz, l1_pts, l2_xyz, idx2, w2, b2,
                                            ss2, l2_pts);
  conv3_kernel<<<128, 256, 0, stream>>>(l2_xyz, l2_pts, w3, b3, h3T);
  bn3max_kernel<<<512, 256, 0, stream>>>(h3T, g3, be3, l3);
  final_kernel<<<8, 256, 0, stream>>>(l3, wf, bf, out);
}

// Round 7
// 1122.072 us; speedup vs baseline: 1.2020x; 1.1004x over previous
//
#include <hip/hip_runtime.h>
#include <hip/hip_bf16.h>
#include <cstddef>
#include <cstdint>

// ---------------------------------------------------------------------------
// PointNet++ encoder for MI355X. Sizes fixed per reference:
// B=8, N1=8192, S1=512 (ns=32, r=0.2), S2=128 (ns=64, r=0.4),
// C1=3->O1=128, C2=131->O2=256, C3=259->O3=512, Z=256.
// ---------------------------------------------------------------------------

__device__ __forceinline__ void fma16(float* acc, float4 a, float4 b) {
  acc[0]  = fmaf(a.x, b.x, acc[0]);
  acc[1]  = fmaf(a.x, b.y, acc[1]);
  acc[2]  = fmaf(a.x, b.z, acc[2]);
  acc[3]  = fmaf(a.x, b.w, acc[3]);
  acc[4]  = fmaf(a.y, b.x, acc[4]);
  acc[5]  = fmaf(a.y, b.y, acc[5]);
  acc[6]  = fmaf(a.y, b.z, acc[6]);
  acc[7]  = fmaf(a.y, b.w, acc[7]);
  acc[8]  = fmaf(a.z, b.x, acc[8]);
  acc[9]  = fmaf(a.z, b.y, acc[9]);
  acc[10] = fmaf(a.z, b.z, acc[10]);
  acc[11] = fmaf(a.z, b.w, acc[11]);
  acc[12] = fmaf(a.w, b.x, acc[12]);
  acc[13] = fmaf(a.w, b.y, acc[13]);
  acc[14] = fmaf(a.w, b.z, acc[14]);
  acc[15] = fmaf(a.w, b.w, acc[15]);
}

// DPP-based max step: v = max(v, dpp_shift(v)). All reduced values are >= 0,
// so bound_ctrl zero-fill is safe. VALU-only (no LDS pipe).
#define DPP_FMAX(v, ctrl)                                                     \
  (v) = fmaxf((v), __int_as_float(__builtin_amdgcn_update_dpp(                \
                 0, __float_as_int(v), (ctrl), 0xf, 0xf, true)))

__device__ __forceinline__ float wave_max_dpp(float v) {
  DPP_FMAX(v, 0x111);  // row_shr:1
  DPP_FMAX(v, 0x112);  // row_shr:2
  DPP_FMAX(v, 0x114);  // row_shr:4
  DPP_FMAX(v, 0x118);  // row_shr:8  -> lane15 of each row = row max
  DPP_FMAX(v, 0x142);  // row_bcast:15
  DPP_FMAX(v, 0x143);  // row_bcast:31 -> lane63 = wave max
  return __int_as_float(__builtin_amdgcn_readlane(__float_as_int(v), 63));
}

__device__ __forceinline__ float readlane_f(float v, int l) {
  return __int_as_float(__builtin_amdgcn_readlane(__float_as_int(v), l));
}

// ---------------------------------------------------------------------------
// FPS (multi-wave): one block per batch, TPB=512 (8 waves). Round-4 reduce
// structure; round-6 change: NO in-loop global stores. Thread-0's per-iter
// out_idx/out_xyz stores forced a vmcnt(0) drain before every s_barrier.
// Picks now land in an LDS history (which doubles as the broadcast buffer)
// and are dumped to global once at the end.
// Selection uses exact bit compares; (wave,lane,slot) lexicographic order ==
// ascending global index == jnp.argmax first-index tie-break. Distance math
// bit-identical to reference (plain f32 ops, same association).
// NOTE (R5): packed-f32 scan + single-barrier variant regressed; keep this.
// ---------------------------------------------------------------------------
template<int N, int NPOINT, int TPB>
__launch_bounds__(TPB)
__global__ void fps_kernel(const float* __restrict__ xyz,
                           int* __restrict__ out_idx,
                           float* __restrict__ out_xyz) {
  constexpr int PPT = N / TPB;
  constexpr int NW = TPB / 64;
  static_assert(NW == 8, "cross-wave DPP reduce assumes 8 waves");
  __shared__ float s_wval[NW];
  __shared__ __align__(16) float4 s_hist[NPOINT];  // (idx_bits, x, y, z)
  const int b = blockIdx.x;
  const int t = threadIdx.x;
  const int lane = t & 63;
  const int wid = t >> 6;
  const float* xb = xyz + (size_t)b * N * 3;
  float px[PPT], py[PPT], pz[PPT], dist[PPT];
#pragma unroll
  for (int j = 0; j < PPT; ++j) {
    const int n = t * PPT + j;
    px[j] = xb[n * 3 + 0];
    py[j] = xb[n * 3 + 1];
    pz[j] = xb[n * 3 + 2];
    dist[j] = 1e10f;
  }
  float cx = xb[0], cy = xb[1], cz = xb[2];
  if (t == 0) s_hist[0] = make_float4(__int_as_float(0), cx, cy, cz);
  for (int i = 0; i < NPOINT - 1; ++i) {
    // Value-only scan: update min-dist, track local max (all values >= 0).
    float m = -1.0f;
#pragma unroll
    for (int j = 0; j < PPT; ++j) {
      const float dx = __fsub_rn(px[j], cx);
      const float dy = __fsub_rn(py[j], cy);
      const float dz = __fsub_rn(pz[j], cz);
      const float d = __fadd_rn(__fadd_rn(__fmul_rn(dx, dx), __fmul_rn(dy, dy)),
                                __fmul_rn(dz, dz));
      const float nd = fminf(dist[j], d);
      dist[j] = nd;
      m = fmaxf(m, nd);
    }
    const float wv = wave_max_dpp(m);
    if (lane == 0) s_wval[wid] = wv;
    __syncthreads();
    // Winner value: each lane reads one wave max (pattern repeats per 8
    // lanes), 3-level DPP row reduce; lane7 of row0 = global winner.
    float x = s_wval[lane & 7];
    float y = x;
    DPP_FMAX(y, 0x111);
    DPP_FMAX(y, 0x112);
    DPP_FMAX(y, 0x114);
    const float winner =
        __int_as_float(__builtin_amdgcn_readlane(__float_as_int(y), 7));
    const unsigned long long wmask = __ballot(x == winner);
    const int first_w = __ffsll(wmask) - 1;
    if (wid == first_w) {
      const unsigned long long cand = __ballot(m == winner);
      const int fl = __ffsll(cand) - 1;
      if (lane == fl) {
        int fj = 0;
        float fx = px[0], fy = py[0], fz = pz[0];
        bool found = (dist[0] == winner);
#pragma unroll
        for (int j = 1; j < PPT; ++j) {
          const bool hit = !found && (dist[j] == winner);
          if (hit) { fj = j; fx = px[j]; fy = py[j]; fz = pz[j]; found = true; }
        }
        s_hist[i + 1] = make_float4(__int_as_float(t * PPT + fj), fx, fy, fz);
      }
    }
    __syncthreads();
    const float4 pk = s_hist[i + 1];
    cx = pk.y; cy = pk.z; cz = pk.w;
  }
  // Batched dump (the loop's final barrier makes all hist writes visible).
  for (int e = t; e < NPOINT; e += TPB) {
    const float4 h = s_hist[e];
    out_idx[b * NPOINT + e] = __float_as_int(h.x);
    float* o = out_xyz + ((size_t)b * NPOINT + e) * 3;
    o[0] = h.y; o[1] = h.z; o[2] = h.w;
  }
}

// ---------------------------------------------------------------------------
// FPS (single-wave): N small enough for one wave (PPT = N/64 slots/lane).
// No LDS, no barriers (stores never precede a barrier -> no drain).
// ---------------------------------------------------------------------------
template<int N, int NPOINT>
__launch_bounds__(64)
__global__ void wave_fps_kernel(const float* __restrict__ xyz,
                                int* __restrict__ out_idx,
                                float* __restrict__ out_xyz) {
  constexpr int PPT = N / 64;
  const int b = blockIdx.x;
  const int lane = threadIdx.x;
  const float* xb = xyz + (size_t)b * N * 3;
  float px[PPT], py[PPT], pz[PPT], dist[PPT];
#pragma unroll
  for (int j = 0; j < PPT; ++j) {
    const int n = lane * PPT + j;
    px[j] = xb[n * 3 + 0];
    py[j] = xb[n * 3 + 1];
    pz[j] = xb[n * 3 + 2];
    dist[j] = 1e10f;
  }
  int far = 0;
  float cx = xb[0], cy = xb[1], cz = xb[2];
  for (int i = 0; i < NPOINT; ++i) {
    if (lane == 0) {
      out_idx[b * NPOINT + i] = far;
      float* o = out_xyz + ((size_t)b * NPOINT + i) * 3;
      o[0] = cx; o[1] = cy; o[2] = cz;
    }
    float m = -1.0f;
    int mj = 0;
    float mx = px[0], my = py[0], mz = pz[0];
#pragma unroll
    for (int j = 0; j < PPT; ++j) {
      const float dx = __fsub_rn(px[j], cx);
      const float dy = __fsub_rn(py[j], cy);
      const float dz = __fsub_rn(pz[j], cz);
      const float d = __fadd_rn(__fadd_rn(__fmul_rn(dx, dx), __fmul_rn(dy, dy)),
                                __fmul_rn(dz, dz));
      const float nd = fminf(dist[j], d);
      dist[j] = nd;
      const bool better = nd > m;  // strict: first slot wins ties
      m = better ? nd : m;
      mj = better ? j : mj;
      mx = better ? px[j] : mx;
      my = better ? py[j] : my;
      mz = better ? pz[j] : mz;
    }
    const float wv = wave_max_dpp(m);
    const unsigned long long cand = __ballot(m == wv);
    const int fl = __ffsll(cand) - 1;  // first lane == smallest global index
    far = __builtin_amdgcn_readlane(lane * PPT + mj, fl);
    cx = readlane_f(mx, fl);
    cy = readlane_f(my, fl);
    cz = readlane_f(mz, fl);
  }
}

// ---------------------------------------------------------------------------
// Ball query: one wave per (b,s). Stream-compact ascending indices whose
// sqrdist (reference cancellation formula) <= r^2; fill remainder with first.
// ---------------------------------------------------------------------------
template<int N, int S, int NS>
__global__ void ballq_kernel(const float* __restrict__ xyz,
                             const float* __restrict__ new_xyz,
                             int* __restrict__ out_idx,
                             float r2) {
  const int gw = (blockIdx.x * blockDim.x + threadIdx.x) >> 6;
  const int lane = threadIdx.x & 63;
  if (gw >= 8 * S) return;
  const int b = gw / S;
  const int s = gw % S;
  const float* c = new_xyz + ((size_t)b * S + s) * 3;
  const float cx = c[0], cy = c[1], cz = c[2];
  const float sa = __fadd_rn(__fadd_rn(__fmul_rn(cx, cx), __fmul_rn(cy, cy)),
                             __fmul_rn(cz, cz));
  const float* xb = xyz + (size_t)b * N * 3;
  int* out = out_idx + ((size_t)b * S + s) * NS;
  int cnt = 0;
  int first = -1;
  for (int n0 = 0; n0 < N && cnt < NS; n0 += 64) {
    const int n = n0 + lane;
    const float x = xb[n * 3 + 0];
    const float y = xb[n * 3 + 1];
    const float z = xb[n * 3 + 2];
    const float sb = __fadd_rn(__fadd_rn(__fmul_rn(x, x), __fmul_rn(y, y)),
                               __fmul_rn(z, z));
    const float dt = __fadd_rn(__fadd_rn(__fmul_rn(x, cx), __fmul_rn(y, cy)),
                               __fmul_rn(z, cz));
    const float d = __fsub_rn(__fadd_rn(sa, sb), __fmul_rn(2.0f, dt));
    const bool in = !(d > r2);
    const unsigned long long m = __ballot(in);
    if (in) {
      const int pos = cnt + __popcll(m & ((1ull << lane) - 1ull));
      if (pos < NS) out[pos] = n;
    }
    if (first < 0 && m) first = n0 + __ffsll((unsigned long long)m) - 1;
    cnt += __popcll(m);
  }
  for (int j = cnt + lane; j < NS; j += 64) out[j] = first;
}

// ---------------------------------------------------------------------------
// Layer-1 moments: x = xyz[idx] - new_xyz  (C=3). 9 sums per block -> partials.
// ---------------------------------------------------------------------------
__global__ void mom1_kernel(const float* __restrict__ xyz,
                            const float* __restrict__ l1_xyz,
                            const int* __restrict__ idx1,
                            float* __restrict__ part) {
  const int t = threadIdx.x;
  const int r = blockIdx.x * 256 + t;   // 0..131071
  const int bs = r >> 5;
  const int b = r >> 14;
  const int idx = idx1[r];
  const float* p = xyz + ((size_t)(b << 13) + idx) * 3;
  const float* q = l1_xyz + (size_t)bs * 3;
  const float x = p[0] - q[0];
  const float y = p[1] - q[1];
  const float z = p[2] - q[2];
  float vals[9] = {x, y, z, x * x, x * y, x * z, y * y, y * z, z * z};
  __shared__ float sw[4][9];
  const int lane = t & 63, wid = t >> 6;
#pragma unroll
  for (int v = 0; v < 9; ++v) {
    float a = vals[v];
#pragma unroll
    for (int off = 32; off; off >>= 1) a += __shfl_xor(a, off);
    if (lane == 0) sw[wid][v] = a;
  }
  __syncthreads();
  if (t == 0) {
#pragma unroll
    for (int v = 0; v < 9; ++v)
      part[blockIdx.x * 12 + v] = sw[0][v] + sw[1][v] + sw[2][v] + sw[3][v];
  }
}

__global__ void stats1_kernel(const float* __restrict__ part,
                              const float* __restrict__ w1,
                              const float* __restrict__ b1,
                              const float* __restrict__ g1,
                              const float* __restrict__ be1,
                              float* __restrict__ ss1) {
  __shared__ double sm[9];
  const int t = threadIdx.x;
  if (t < 9) {
    double a = 0.0;
    for (int k = 0; k < 512; ++k) a += (double)part[k * 12 + t];
    sm[t] = a;
  }
  __syncthreads();
  const double n = 131072.0;
  const double mu0 = sm[0] / n, mu1 = sm[1] / n, mu2 = sm[2] / n;
  const double C00 = sm[3] / n - mu0 * mu0;
  const double C01 = sm[4] / n - mu0 * mu1;
  const double C02 = sm[5] / n - mu0 * mu2;
  const double C11 = sm[6] / n - mu1 * mu1;
  const double C12 = sm[7] / n - mu1 * mu2;
  const double C22 = sm[8] / n - mu2 * mu2;
  if (t < 128) {
    const double w0 = w1[t * 3], w1_ = w1[t * 3 + 1], w2 = w1[t * 3 + 2];
    const double mh = w0 * mu0 + w1_ * mu1 + w2 * mu2 + (double)b1[t];
    const double var = w0 * w0 * C00 + w1_ * w1_ * C11 + w2 * w2 * C22 +
                       2.0 * (w0 * w1_ * C01 + w0 * w2 * C02 + w1_ * w2 * C12);
    const float scale = g1[t] / sqrtf((float)var + 1e-5f);
    const float shift = be1[t] - (float)mh * scale;
    ss1[t * 2] = scale;
    ss1[t * 2 + 1] = shift;
  }
}

// ---------------------------------------------------------------------------
// Layer-1 fused conv+BN+relu+max: one block per (b,s), thread = channel o.
// ---------------------------------------------------------------------------
__global__ void conv1max_kernel(const float* __restrict__ xyz,
                                const float* __restrict__ l1_xyz,
                                const int* __restrict__ idx1,
                                const float* __restrict__ w1,
                                const float* __restrict__ b1,
                                const float* __restrict__ ss1,
                                float* __restrict__ l1_pts) {
  const int bs = blockIdx.x;
  const int b = bs >> 9;
  const int t = threadIdx.x;  // 128
  __shared__ float sx[32][3];
  if (t < 32) {
    const int idx = idx1[bs * 32 + t];
    const float* p = xyz + ((size_t)(b << 13) + idx) * 3;
    const float* q = l1_xyz + (size_t)bs * 3;
    sx[t][0] = p[0] - q[0];
    sx[t][1] = p[1] - q[1];
    sx[t][2] = p[2] - q[2];
  }
  __syncthreads();
  const float w0 = w1[t * 3], wa = w1[t * 3 + 1], wb = w1[t * 3 + 2];
  const float bo = b1[t];
  float hmax = -1e30f, hmin = 1e30f;
#pragma unroll 8
  for (int k = 0; k < 32; ++k) {
    const float h = sx[k][0] * w0 + sx[k][1] * wa + sx[k][2] * wb + bo;
    hmax = fmaxf(hmax, h);
    hmin = fminf(hmin, h);
  }
  const float scale = ss1[t * 2], shift = ss1[t * 2 + 1];
  const float hsel = (scale >= 0.f) ? hmax : hmin;
  l1_pts[(size_t)bs * 128 + t] = fmaxf(hsel * scale + shift, 0.0f);
}

// ---------------------------------------------------------------------------
// Layer-2 moments v2: symmetric X^T X via upper-triangle 8x8 octet tiles
// (17x18/2 = 153 tiles, one pass over 256 threads), mirrored on write.
// Per-element accumulation order identical to v1 -> bitwise-identical partials.
// ---------------------------------------------------------------------------
#define MOM2_BLOCKS 256
#define MOM2_S2 (132 * 132)            // 17424
#define MOM2_STRIDE (MOM2_S2 + 132)    // 17556

__global__ __launch_bounds__(256)
void mom2_kernel(const float* __restrict__ l1_xyz,
                 const float* __restrict__ l1_pts,
                 const float* __restrict__ l2_xyz,
                 const int* __restrict__ idx2,
                 float* __restrict__ part) {
  __shared__ __align__(16) float xs[64 * 136];  // cols 131..135 zero-padded
  const int t = threadIdx.x;
  const int blk = blockIdx.x;
  // Triangular octet-tile map: t -> (ti, tj), ti <= tj, 17 octets.
  int ti = -1, tj = 0;
  {
    int u = t;
    for (int r = 0; r < 17; ++r) {
      const int cnt = 17 - r;
      if (u < cnt) { ti = r; tj = r + u; break; }
      u -= cnt;
    }
  }
  const bool active = (ti >= 0);  // t < 153
  float acc[64];
#pragma unroll
  for (int j = 0; j < 64; ++j) acc[j] = 0.f;
  float s1 = 0.f;
  const int rbase = blk * 256;
  for (int sb = 0; sb < 4; ++sb) {
    __syncthreads();
    for (int e = t; e < 64 * 136; e += 256) {
      const int rr = e / 136, cc = e % 136;
      const int r = rbase + sb * 64 + rr;
      const int b = r >> 13;
      const int s = (r >> 6) & 127;
      const int idx = idx2[r];
      float v = 0.f;
      if (cc < 3)
        v = l1_xyz[((size_t)(b << 9) + idx) * 3 + cc] -
            l2_xyz[((size_t)(b << 7) + s) * 3 + cc];
      else if (cc < 131)
        v = l1_pts[((size_t)(b << 9) + idx) * 128 + (cc - 3)];
      xs[rr * 136 + cc] = v;
    }
    __syncthreads();
    if (active) {
      for (int r = 0; r < 64; ++r) {
        const float4 a0 = *(const float4*)&xs[r * 136 + ti * 8];
        const float4 a1 = *(const float4*)&xs[r * 136 + ti * 8 + 4];
        const float4 b0 = *(const float4*)&xs[r * 136 + tj * 8];
        const float4 b1 = *(const float4*)&xs[r * 136 + tj * 8 + 4];
        fma16(acc + 0,  a0, b0);
        fma16(acc + 16, a0, b1);
        fma16(acc + 32, a1, b0);
        fma16(acc + 48, a1, b1);
      }
    }
    if (t < 132) {
      for (int r = 0; r < 64; ++r) s1 += xs[r * 136 + t];
    }
  }
  float* pb = part + (size_t)blk * MOM2_STRIDE;
  if (active) {
#pragma unroll
    for (int ii = 0; ii < 8; ++ii) {
      const int gi = ti * 8 + ii;
      if (gi < 132) {
#pragma unroll
        for (int jj = 0; jj < 8; ++jj) {
          const int gj = tj * 8 + jj;
          if (gj < 132) {
            const float v =
                acc[(ii >> 2) * 32 + (jj >> 2) * 16 + (ii & 3) * 4 + (jj & 3)];
            pb[gi * 132 + gj] = v;
            if (ti != tj) pb[gj * 132 + gi] = v;  // x_i*x_j commutes: bitwise ==
          }
        }
      }
    }
  }
  if (t < 132) pb[MOM2_S2 + t] = s1;
}

__global__ void reduce2_kernel(const float* __restrict__ part,
                               double* __restrict__ out) {
  const int e = blockIdx.x * 256 + threadIdx.x;
  if (e >= MOM2_STRIDE) return;
  double a = 0.0;
  for (int k = 0; k < MOM2_BLOCKS; ++k)
    a += (double)part[(size_t)k * MOM2_STRIDE + e];
  out[e] = a;
}

__global__ void stats2_kernel(const double* __restrict__ mom,
                              const float* __restrict__ w2,
                              const float* __restrict__ b2,
                              const float* __restrict__ g2,
                              const float* __restrict__ be2,
                              float* __restrict__ ss2) {
  const int o = blockIdx.x;
  const int t = threadIdx.x;  // 128
  const float* w = w2 + o * 131;
  double q = 0.0, md = 0.0;
  for (int i = t; i < 131; i += 128) {
    const double wi = (double)w[i];
    double di = 0.0;
    for (int j = 0; j < 131; ++j) di += mom[i * 132 + j] * (double)w[j];
    q += wi * di;
    md += wi * mom[MOM2_S2 + i];
  }
  __shared__ double sq[128], smd[128];
  sq[t] = q;
  smd[t] = md;
  __syncthreads();
  for (int off = 64; off; off >>= 1) {
    if (t < off) { sq[t] += sq[t + off]; smd[t] += smd[t + off]; }
    __syncthreads();
  }
  if (t == 0) {
    const double n = 65536.0;
    const double mdot = smd[0] / n;
    const double var = sq[0] / n - mdot * mdot;
    const double mean = mdot + (double)b2[o];
    const float scale = g2[o] / sqrtf((float)var + 1e-5f);
    const float shift = be2[o] - (float)mean * scale;
    ss2[o * 2] = scale;
    ss2[o * 2 + 1] = shift;
  }
}

// ---------------------------------------------------------------------------
// Layer-2 fused conv+BN+relu+max v2: block per (b,s), 256 threads.
// Thread tile 8k x 8o (quads at tx*4 and 128+tx*4 keep lane-contiguous LDS
// reads); c staged in 4 chunks (33,33,33,32). LDS bytes/FLOP halved vs v1.
// Per-o c-accumulation order unchanged -> bitwise-identical output.
// ---------------------------------------------------------------------------
__global__ __launch_bounds__(256)
void conv2max_kernel(const float* __restrict__ l1_xyz,
                     const float* __restrict__ l1_pts,
                     const float* __restrict__ l2_xyz,
                     const int* __restrict__ idx2,
                     const float* __restrict__ w2,
                     const float* __restrict__ b2,
                     const float* __restrict__ ss2,
                     float* __restrict__ l2_pts) {
  __shared__ __align__(16) float xT[33 * 68];    // [cc][k]
  __shared__ __align__(16) float wT[33 * 260];   // [cc][o]
  __shared__ float redmax[8 * 256];
  __shared__ float redmin[8 * 256];
  const int bs = blockIdx.x;  // b*128+s
  const int b = bs >> 7;
  const int t = threadIdx.x;
  const int ty = t >> 5;   // 0..7  k-octet
  const int tx = t & 31;   // 0..31 o-quad pair
  float acc[64];
#pragma unroll
  for (int j = 0; j < 64; ++j) acc[j] = 0.f;
  for (int ch = 0; ch < 4; ++ch) {
    const int c0 = ch * 33;
    const int CC = (ch == 3) ? 32 : 33;
    __syncthreads();
    for (int e = t; e < 64 * CC; e += 256) {
      const int k = e / CC, cc = e % CC;
      const int idx = idx2[bs * 64 + k];
      const int c = c0 + cc;
      float v;
      if (c < 3)
        v = l1_xyz[((size_t)(b << 9) + idx) * 3 + c] -
            l2_xyz[(size_t)bs * 3 + c];
      else
        v = l1_pts[((size_t)(b << 9) + idx) * 128 + (c - 3)];
      xT[cc * 68 + k] = v;
    }
    for (int e = t; e < 256 * CC; e += 256) {
      const int oo = e / CC, cc = e % CC;
      wT[cc * 260 + oo] = w2[oo * 131 + c0 + cc];
    }
    __syncthreads();
    for (int cc = 0; cc < CC; ++cc) {
      const float4 a0 = *(const float4*)&xT[cc * 68 + ty * 8];
      const float4 a1 = *(const float4*)&xT[cc * 68 + ty * 8 + 4];
      const float4 w0 = *(const float4*)&wT[cc * 260 + tx * 4];
      const float4 w1 = *(const float4*)&wT[cc * 260 + 128 + tx * 4];
      fma16(acc + 0,  a0, w0);
      fma16(acc + 16, a0, w1);
      fma16(acc + 32, a1, w0);
      fma16(acc + 48, a1, w1);
    }
  }
  // Per-thread max/min over its 8 k for each of its 8 o.
#pragma unroll
  for (int bi = 0; bi < 4; ++bi) {
    float mxA = acc[bi], mnA = acc[bi];
    float mxB = acc[16 + bi], mnB = acc[16 + bi];
#pragma unroll
    for (int ai = 1; ai < 4; ++ai) {
      mxA = fmaxf(mxA, acc[ai * 4 + bi]);
      mnA = fminf(mnA, acc[ai * 4 + bi]);
      mxB = fmaxf(mxB, acc[16 + ai * 4 + bi]);
      mnB = fminf(mnB, acc[16 + ai * 4 + bi]);
    }
#pragma unroll
    for (int ai = 0; ai < 4; ++ai) {
      mxA = fmaxf(mxA, acc[32 + ai * 4 + bi]);
      mnA = fminf(mnA, acc[32 + ai * 4 + bi]);
      mxB = fmaxf(mxB, acc[48 + ai * 4 + bi]);
      mnB = fminf(mnB, acc[48 + ai * 4 + bi]);
    }
    redmax[ty * 256 + tx * 4 + bi] = mxA;
    redmin[ty * 256 + tx * 4 + bi] = mnA;
    redmax[ty * 256 + 128 + tx * 4 + bi] = mxB;
    redmin[ty * 256 + 128 + tx * 4 + bi] = mnB;
  }
  __syncthreads();
  {
    const int o = t;
    float mx = redmax[o], mn = redmin[o];
#pragma unroll
    for (int w = 1; w < 8; ++w) {
      mx = fmaxf(mx, redmax[w * 256 + o]);
      mn = fminf(mn, redmin[w * 256 + o]);
    }
    const float bo = b2[o];
    const float hmax = mx + bo;
    const float hmin = mn + bo;
    const float scale = ss2[o * 2], shift = ss2[o * 2 + 1];
    const float hsel = (scale >= 0.f) ? hmax : hmin;
    l2_pts[(size_t)bs * 256 + o] = fmaxf(hsel * scale + shift, 0.f);
  }
}

// ---------------------------------------------------------------------------
// Layer-3 GEMM: h3T[o][r] = dot(x3[r], w3[o]) + b3[o]; r=b*128+k (1024),
// o (512), K=259 in chunks of 96 (zero-padded). Output transposed for stats.
// ---------------------------------------------------------------------------
__global__ __launch_bounds__(256)
void conv3_kernel(const float* __restrict__ l2_xyz,
                  const float* __restrict__ l2_pts,
                  const float* __restrict__ w3,
                  const float* __restrict__ b3,
                  float* __restrict__ h3T) {
  __shared__ __align__(16) float aT[96 * 68];  // [cc][rr] stride 68
  __shared__ __align__(16) float wT[96 * 68];  // [cc][oo] stride 68
  const int t = threadIdx.x;
  const int r0 = (blockIdx.x & 15) * 64;
  const int o0 = (blockIdx.x >> 4) * 64;
  const int ty = t >> 4, tx = t & 15;
  float acc[16];
#pragma unroll
  for (int j = 0; j < 16; ++j) acc[j] = 0.f;
  for (int c0 = 0; c0 < 259; c0 += 96) {
    __syncthreads();
    for (int e = t; e < 96 * 64; e += 256) {
      const int rr = e / 96, cc = e - rr * 96;
      const int c = c0 + cc;
      const int r = r0 + rr;
      float v = 0.f;
      if (c < 259)
        v = (c < 3) ? l2_xyz[(size_t)r * 3 + c]
                    : l2_pts[(size_t)r * 256 + (c - 3)];
      aT[cc * 68 + rr] = v;
    }
    for (int e = t; e < 96 * 64; e += 256) {
      const int oo = e / 96, cc = e - oo * 96;
      const int c = c0 + cc;
      wT[cc * 68 + oo] = (c < 259) ? w3[(size_t)(o0 + oo) * 259 + c] : 0.f;
    }
    __syncthreads();
    for (int cc = 0; cc < 96; ++cc) {
      const float4 a = *(const float4*)&aT[cc * 68 + ty * 4];
      const float4 w4 = *(const float4*)&wT[cc * 68 + tx * 4];
      fma16(acc, a, w4);
    }
  }
#pragma unroll
  for (int kk = 0; kk < 4; ++kk)
#pragma unroll
    for (int oo = 0; oo < 4; ++oo) {
      const int o = o0 + tx * 4 + oo;
      const int r = r0 + ty * 4 + kk;
      h3T[(size_t)o * 1024 + r] = acc[kk * 4 + oo] + b3[o];
    }
}

// ---------------------------------------------------------------------------
// Layer-3 BN stats + relu + per-batch max, fused. Block per channel o.
// ---------------------------------------------------------------------------
__global__ void bn3max_kernel(const float* __restrict__ h3T,
                              const float* __restrict__ g3,
                              const float* __restrict__ be3,
                              float* __restrict__ l3) {
  const int o = blockIdx.x;
  const int t = threadIdx.x;  // 256
  const float4 v = *(const float4*)&h3T[(size_t)o * 1024 + t * 4];
  double s = (double)v.x + (double)v.y + (double)v.z + (double)v.w;
  double s2 = (double)v.x * v.x + (double)v.y * v.y + (double)v.z * v.z +
              (double)v.w * v.w;
  __shared__ double sa_[256], sb_[256];
  sa_[t] = s;
  sb_[t] = s2;
  __syncthreads();
  for (int off = 128; off; off >>= 1) {
    if (t < off) { sa_[t] += sa_[t + off]; sb_[t] += sb_[t + off]; }
    __syncthreads();
  }
  const double mean = sa_[0] / 1024.0;
  const double var = sb_[0] / 1024.0 - mean * mean;
  const float scale = g3[o] / sqrtf((float)var + 1e-5f);
  const float shift = be3[o] - (float)mean * scale;
  const float hmax = fmaxf(fmaxf(v.x, v.y), fmaxf(v.z, v.w));
  const float hmin = fminf(fminf(v.x, v.y), fminf(v.z, v.w));
  const float hsel = (scale >= 0.f) ? hmax : hmin;
  __shared__ float rm[256];
  rm[t] = fmaxf(hsel * scale + shift, 0.f);
  __syncthreads();
  if (t < 8) {
    float m = rm[t * 32];
#pragma unroll
    for (int j = 1; j < 32; ++j) m = fmaxf(m, rm[t * 32 + j]);
    l3[t * 512 + o] = m;
  }
}

__global__ void final_kernel(const float* __restrict__ l3,
                             const float* __restrict__ wf,
                             const float* __restrict__ bf,
                             float* __restrict__ out) {
  const int b = blockIdx.x;
  const int t = threadIdx.x;  // 256
  __shared__ float s[512];
  s[t] = l3[b * 512 + t];
  s[t + 256] = l3[b * 512 + t + 256];
  __syncthreads();
  float acc = bf[t];
  for (int o = 0; o < 512; ++o) acc = fmaf(wf[(size_t)t * 512 + o], s[o], acc);
  out[b * 256 + t] = acc;
}

// ---------------------------------------------------------------------------
extern "C" void kernel_launch(void* const* d_in, const int* in_sizes, int n_in,
                              void* d_out, int out_size, void* d_ws, size_t ws_size,
                              hipStream_t stream) {
  (void)in_sizes; (void)n_in; (void)out_size; (void)ws_size;
  const float* xyz = (const float*)d_in[0];
  const float* w1 = (const float*)d_in[1];
  const float* b1 = (const float*)d_in[2];
  const float* g1 = (const float*)d_in[3];
  const float* be1 = (const float*)d_in[4];
  const float* w2 = (const float*)d_in[5];
  const float* b2 = (const float*)d_in[6];
  const float* g2 = (const float*)d_in[7];
  const float* be2 = (const float*)d_in[8];
  const float* w3 = (const float*)d_in[9];
  const float* b3 = (const float*)d_in[10];
  const float* g3 = (const float*)d_in[11];
  const float* be3 = (const float*)d_in[12];
  const float* wf = (const float*)d_in[13];
  const float* bf = (const float*)d_in[14];
  float* out = (float*)d_out;

  char* base = (char*)d_ws;
  size_t off = 0;
  auto alloc = [&](size_t bytes) -> char* {
    off = (off + 511) & ~(size_t)511;
    char* p = base + off;
    off += bytes;
    return p;
  };
  int* fps1_idx = (int*)alloc(8 * 512 * 4);
  float* l1_xyz = (float*)alloc(8 * 512 * 3 * 4);
  int* idx1 = (int*)alloc((size_t)8 * 512 * 32 * 4);
  float* part1 = (float*)alloc(512 * 12 * 4);
  float* ss1 = (float*)alloc(128 * 2 * 4);
  float* l1_pts = (float*)alloc((size_t)8 * 512 * 128 * 4);
  int* fps2_idx = (int*)alloc(8 * 128 * 4);
  float* l2_xyz = (float*)alloc(8 * 128 * 3 * 4);
  int* idx2 = (int*)alloc((size_t)8 * 128 * 64 * 4);
  float* part2 = (float*)alloc((size_t)MOM2_BLOCKS * MOM2_STRIDE * 4);
  double* mom2d = (double*)alloc((size_t)MOM2_STRIDE * 8);
  float* ss2 = (float*)alloc(256 * 2 * 4);
  float* l2_pts = (float*)alloc((size_t)8 * 128 * 256 * 4);
  float* h3T = (float*)alloc((size_t)512 * 1024 * 4);
  float* l3 = (float*)alloc(8 * 512 * 4);

  // Match JAX weak-type promotion: radius*radius in double, then cast to f32.
  const float r2_1 = (float)(0.2 * 0.2);
  const float r2_2 = (float)(0.4 * 0.4);

  fps_kernel<8192, 512, 512><<<8, 512, 0, stream>>>(xyz, fps1_idx, l1_xyz);
  ballq_kernel<8192, 512, 32><<<1024, 256, 0, stream>>>(xyz, l1_xyz, idx1, r2_1);
  mom1_kernel<<<512, 256, 0, stream>>>(xyz, l1_xyz, idx1, part1);
  stats1_kernel<<<1, 128, 0, stream>>>(part1, w1, b1, g1, be1, ss1);
  conv1max_kernel<<<4096, 128, 0, stream>>>(xyz, l1_xyz, idx1, w1, b1, ss1, l1_pts);
  wave_fps_kernel<512, 128><<<8, 64, 0, stream>>>(l1_xyz, fps2_idx, l2_xyz);
  ballq_kernel<512, 128, 64><<<256, 256, 0, stream>>>(l1_xyz, l2_xyz, idx2, r2_2);
  mom2_kernel<<<MOM2_BLOCKS, 256, 0, stream>>>(l1_xyz, l1_pts, l2_xyz, idx2, part2);
  reduce2_kernel<<<(MOM2_STRIDE + 255) / 256, 256, 0, stream>>>(part2, mom2d);
  stats2_kernel<<<256, 128, 0, stream>>>(mom2d, w2, b2, g2, be2, ss2);
  conv2max_kernel<<<1024, 256, 0, stream>>>(l1_xyz, l1_pts, l2_xyz, idx2, w2, b2,
                                            ss2, l2_pts);
  conv3_kernel<<<128, 256, 0, stream>>>(l2_xyz, l2_pts, w3, b3, h3T);
  bn3max_kernel<<<512, 256, 0, stream>>>(h3T, g3, be3, l3);
  final_kernel<<<8, 256, 0, stream>>>(l3, wf, bf, out);
}